// Round 5
// baseline (7963.971 us; speedup 1.0000x reference)
//
#include <hip/hip_runtime.h>
#include <hip/hip_cooperative_groups.h>
#include <cfloat>
#include <cmath>

namespace cg = cooperative_groups;

#define N_Q 4096
#define N_S 1600
#define DIM 1024
#define N_C 64
#define KNN 12
#define MAX_ITER 50
#define EPS_CONV 1e-4f
#define NBLK 64          // mm_loop grid size; must match launch

__device__ __forceinline__ float wave_max64(float v){
  #pragma unroll
  for (int o = 32; o; o >>= 1) v = fmaxf(v, __shfl_xor(v, o, 64));
  return v;
}
__device__ __forceinline__ float wave_sum64(float v){
  #pragma unroll
  for (int o = 32; o; o >>= 1) v += __shfl_xor(v, o, 64);
  return v;
}
__device__ __forceinline__ float wave_min64(float v){
  #pragma unroll
  for (int o = 32; o; o >>= 1) v = fminf(v, __shfl_xor(v, o, 64));
  return v;
}

// ---- prototypes: segment mean over support set, stored TRANSPOSED Pt[f][c];
//      also per-class squared norm pn[c].
__global__ __launch_bounds__(256) void proto_kernel(
    const float* __restrict__ fs, const int* __restrict__ ys,
    float* __restrict__ Pt, float* __restrict__ pn)
{
  const int c = blockIdx.x, t = threadIdx.x;
  float a0 = 0.f, a1 = 0.f, a2 = 0.f, a3 = 0.f;
  int cnt = 0;
  for (int i = 0; i < N_S; i++){
    if (ys[i] == c){
      const float* r = fs + (size_t)i * DIM;
      a0 += r[t]; a1 += r[t + 256]; a2 += r[t + 512]; a3 += r[t + 768];
      cnt++;
    }
  }
  const float inv = 1.0f / fmaxf((float)cnt, 1.0f);
  const float v0 = a0*inv, v1 = a1*inv, v2 = a2*inv, v3 = a3*inv;
  Pt[(t      )*N_C + c] = v0;
  Pt[(t + 256)*N_C + c] = v1;
  Pt[(t + 512)*N_C + c] = v2;
  Pt[(t + 768)*N_C + c] = v3;
  __shared__ float red[256];
  red[t] = v0*v0 + v1*v1 + v2*v2 + v3*v3;
  __syncthreads();
  for (int o = 128; o; o >>= 1){ if (t < o) red[t] += red[t + o]; __syncthreads(); }
  if (t == 0) pn[c] = red[0];
}

// ---- per-row squared norm of feat_q
__global__ __launch_bounds__(256) void rownorm_kernel(
    const float* __restrict__ X, float* __restrict__ qn)
{
  const int i = blockIdx.x, t = threadIdx.x;
  const float* r = X + (size_t)i * DIM;
  float s = r[t]*r[t] + r[t+256]*r[t+256] + r[t+512]*r[t+512] + r[t+768]*r[t+768];
  __shared__ float red[256];
  red[t] = s; __syncthreads();
  for (int o = 128; o; o >>= 1){ if (t < o) red[t] += red[t + o]; __syncthreads(); }
  if (t == 0) qn[i] = red[0];
}

// ---- full pairwise distances, FULL grid (triangular+mirror abandoned: R3/R4
//      both showed 46x HBM write amplification regardless of mirror-store lane
//      pattern; full-grid direct store measured exactly 64 MB writes in R1 and
//      <511 us in R2). BK=16, double-buffered LDS (32 KB): ONE barrier per
//      K-iter, register prefetch overlaps global latency with compute.
__global__ __launch_bounds__(256, 4) void dist_gemm(
    const float* __restrict__ X, const float* __restrict__ qn, float* __restrict__ Dq)
{
  __shared__ float As[2][16][128];
  __shared__ float Bs[2][16][128];
  const int t = threadIdx.x;
  const int w = t >> 6, l = t & 63;
  const int ri = (w >> 1) * 64 + (l >> 3) * 8;   // row offset in tile
  const int cj = (w & 1) * 64 + (l & 7) * 8;     // col offset in tile
  const int i0 = blockIdx.y * 128, j0 = blockIdx.x * 128;
  const int lr = t >> 1, lh = (t & 1) * 8;       // staging: 2 lanes per X-row

  const float* pA = X + (size_t)(i0 + lr) * DIM + lh;
  const float* pB = X + (size_t)(j0 + lr) * DIM + lh;

  float acc[8][8];
  #pragma unroll
  for (int u = 0; u < 8; u++)
    #pragma unroll
    for (int v = 0; v < 8; v++) acc[u][v] = 0.f;

  // stage first K-tile into buffer 0
  float4 ga0 = *(const float4*)(pA);
  float4 ga1 = *(const float4*)(pA + 4);
  float4 gb0 = *(const float4*)(pB);
  float4 gb1 = *(const float4*)(pB + 4);
  As[0][lh+0][lr]=ga0.x; As[0][lh+1][lr]=ga0.y; As[0][lh+2][lr]=ga0.z; As[0][lh+3][lr]=ga0.w;
  As[0][lh+4][lr]=ga1.x; As[0][lh+5][lr]=ga1.y; As[0][lh+6][lr]=ga1.z; As[0][lh+7][lr]=ga1.w;
  Bs[0][lh+0][lr]=gb0.x; Bs[0][lh+1][lr]=gb0.y; Bs[0][lh+2][lr]=gb0.z; Bs[0][lh+3][lr]=gb0.w;
  Bs[0][lh+4][lr]=gb1.x; Bs[0][lh+5][lr]=gb1.y; Bs[0][lh+6][lr]=gb1.z; Bs[0][lh+7][lr]=gb1.w;
  __syncthreads();

  int buf = 0;
  for (int k0 = 16; k0 <= DIM; k0 += 16){
    const bool more = (k0 < DIM);
    if (more){                      // prefetch next K-tile into registers
      ga0 = *(const float4*)(pA + k0);
      ga1 = *(const float4*)(pA + k0 + 4);
      gb0 = *(const float4*)(pB + k0);
      gb1 = *(const float4*)(pB + k0 + 4);
    }
    #pragma unroll
    for (int k = 0; k < 16; k++){
      float4 a0 = *(const float4*)&As[buf][k][ri];
      float4 a1 = *(const float4*)&As[buf][k][ri + 4];
      float4 b0 = *(const float4*)&Bs[buf][k][cj];
      float4 b1 = *(const float4*)&Bs[buf][k][cj + 4];
      float a[8] = {a0.x,a0.y,a0.z,a0.w,a1.x,a1.y,a1.z,a1.w};
      float b[8] = {b0.x,b0.y,b0.z,b0.w,b1.x,b1.y,b1.z,b1.w};
      #pragma unroll
      for (int u = 0; u < 8; u++)
        #pragma unroll
        for (int v = 0; v < 8; v++) acc[u][v] = fmaf(a[u], b[v], acc[u][v]);
    }
    if (more){
      const int nb = buf ^ 1;
      As[nb][lh+0][lr]=ga0.x; As[nb][lh+1][lr]=ga0.y; As[nb][lh+2][lr]=ga0.z; As[nb][lh+3][lr]=ga0.w;
      As[nb][lh+4][lr]=ga1.x; As[nb][lh+5][lr]=ga1.y; As[nb][lh+6][lr]=ga1.z; As[nb][lh+7][lr]=ga1.w;
      Bs[nb][lh+0][lr]=gb0.x; Bs[nb][lh+1][lr]=gb0.y; Bs[nb][lh+2][lr]=gb0.z; Bs[nb][lh+3][lr]=gb0.w;
      Bs[nb][lh+4][lr]=gb1.x; Bs[nb][lh+5][lr]=gb1.y; Bs[nb][lh+6][lr]=gb1.z; Bs[nb][lh+7][lr]=gb1.w;
      __syncthreads();
      buf = nb;
    }
  }

  const float4 qj0 = *(const float4*)&qn[j0 + cj];
  const float4 qj1 = *(const float4*)&qn[j0 + cj + 4];
  const float qj[8] = {qj0.x,qj0.y,qj0.z,qj0.w,qj1.x,qj1.y,qj1.z,qj1.w};
  #pragma unroll
  for (int u = 0; u < 8; u++){
    const int i = i0 + ri + u;
    const float qi = qn[i];
    float o[8];
    #pragma unroll
    for (int v = 0; v < 8; v++)
      o[v] = sqrtf(fmaxf(qi + qj[v] - 2.0f * acc[u][v], 0.f));
    float* dst = &Dq[(size_t)i * N_Q + j0 + cj];
    *(float4*)(dst    ) = make_float4(o[0],o[1],o[2],o[3]);
    *(float4*)(dst + 4) = make_float4(o[4],o[5],o[6],o[7]);
  }
}

// ---- per-row 13 smallest (ties -> smaller index). Row cached in REGISTERS
//      (16 per thread); shfl wave-reduce; 2 syncthreads per pass.
__global__ __launch_bounds__(256) void topk_kernel(
    const float* __restrict__ Dq, int* __restrict__ nbr,
    float* __restrict__ dnbr, float* __restrict__ sigma)
{
  const int i = blockIdx.x, t = threadIdx.x;
  const float* row = Dq + (size_t)i * N_Q;
  float r[16];
  #pragma unroll
  for (int u = 0; u < 16; u++) r[u] = row[t + u * 256];

  __shared__ float pvf[4];
  __shared__ int   pif[4];
  __shared__ int   bwi_s;

  for (int s = 0; s < KNN + 1; s++){
    float best = FLT_MAX; int bj = 0x7fffffff;
    #pragma unroll
    for (int u = 0; u < 16; u++){
      float v = r[u];
      if (v < best){ best = v; bj = t + u * 256; }   // ascending j: strict < keeps earliest
    }
    #pragma unroll
    for (int o = 32; o; o >>= 1){
      float ov = __shfl_xor(best, o, 64); int oj = __shfl_xor(bj, o, 64);
      if (ov < best || (ov == best && oj < bj)){ best = ov; bj = oj; }
    }
    if ((t & 63) == 0){ pvf[t >> 6] = best; pif[t >> 6] = bj; }
    __syncthreads();
    if (t == 0){
      float bv = pvf[0]; int bi2 = pif[0];
      #pragma unroll
      for (int w2 = 1; w2 < 4; w2++){
        float v2 = pvf[w2]; int i2 = pif[w2];
        if (v2 < bv || (v2 == bv && i2 < bi2)){ bv = v2; bi2 = i2; }
      }
      bwi_s = bi2;
      if (s >= 1){ nbr[i*KNN + s - 1] = bi2; dnbr[i*KNN + s - 1] = bv; }
      if (s == KNN) sigma[i] = bv + 1e-8f;
    }
    __syncthreads();
    const int widx = bwi_s;
    if ((widx & 255) == t) r[widx >> 8] = FLT_MAX;   // owner invalidates (registers)
  }
}

// ---- a[i][c] = clamped sqdist(query i, proto c); d2min[i] = min_c a[i][c]
__global__ __launch_bounds__(64) void a_kernel(
    const float* __restrict__ Xq, const float* __restrict__ Pt,
    const float* __restrict__ qn, const float* __restrict__ pn,
    float* __restrict__ aM, float* __restrict__ d2min)
{
  const int i = blockIdx.x, c = threadIdx.x;
  __shared__ float x[DIM];
  const float* r = Xq + (size_t)i * DIM;
  for (int f = c; f < DIM; f += 64) x[f] = r[f];
  __syncthreads();
  float dot = 0.f;
  #pragma unroll 4
  for (int f = 0; f < DIM; f++) dot = fmaf(x[f], Pt[f*N_C + c], dot);
  float d2 = fmaxf(qn[i] + pn[c] - 2.0f * dot, 0.0f);
  aM[i*N_C + c] = d2;
  float m = wave_min64(d2);
  if (c == 0) d2min[i] = m;
}

// ---- median of d = sqrt(d2min) via single-block bitonic sort of 4096
__global__ __launch_bounds__(1024) void median_kernel(
    const float* __restrict__ d2min, float* __restrict__ denom)
{
  __shared__ float s[N_Q];
  const int t = threadIdx.x;
  for (int j = t; j < N_Q; j += 1024) s[j] = sqrtf(d2min[j]);
  __syncthreads();
  for (int ksz = 2; ksz <= N_Q; ksz <<= 1){
    for (int st = ksz >> 1; st > 0; st >>= 1){
      for (int i = t; i < N_Q; i += 1024){
        int j = i ^ st;
        if (j > i){
          float a = s[i], b = s[j];
          bool up = ((i & ksz) == 0);
          if (up ? (a > b) : (a < b)){ s[i] = b; s[j] = a; }
        }
      }
      __syncthreads();
    }
  }
  if (t == 0){
    float med = 0.5f * (s[N_Q/2 - 1] + s[N_Q/2]);
    denom[0] = 2.0f * med * med + 1e-8f;
  }
}

// ---- halved edge weights, symmetric row sums, in-degree counts
__global__ __launch_bounds__(256) void wdeg_kernel(
    const int* __restrict__ nbr, const float* __restrict__ dnbr,
    const float* __restrict__ sigma, float* __restrict__ wh,
    float* __restrict__ rowsum, int* __restrict__ indeg)
{
  const int e = blockIdx.x * 256 + threadIdx.x;
  if (e >= N_Q * KNN) return;
  const int i = e / KNN;
  const int j = nbr[e];
  float w = 0.5f * expf(-dnbr[e] / (sigma[i] * sigma[j]));
  wh[e] = w;
  atomicAdd(&rowsum[i], w);
  atomicAdd(&rowsum[j], w);
  atomicAdd(&indeg[j], 1);
}

// ---- CSR row pointers: deg[r] = 12 (out) + indeg[r] (in)
__global__ __launch_bounds__(256) void scan_kernel(
    const int* __restrict__ indeg, int* __restrict__ rowptr)
{
  __shared__ int part[256];
  const int t = threadIdx.x;
  const int base = t * 16;
  int loc[16];
  int lsum = 0;
  for (int u = 0; u < 16; u++){ loc[u] = lsum; lsum += indeg[base + u]; }
  part[t] = lsum; __syncthreads();
  if (t == 0){
    int run = 0;
    for (int q = 0; q < 256; q++){ int v = part[q]; part[q] = run; run += v; }
  }
  __syncthreads();
  const int off = part[t];
  for (int u = 0; u < 16; u++){
    int r = base + u;
    rowptr[r] = KNN * r + off + loc[u];
  }
  if (t == 255) rowptr[N_Q] = KNN * N_Q + off + lsum;
}

// ---- CSR fill: out-edges in fixed slots, in-edges via per-row atomic cursor
__global__ __launch_bounds__(256) void fill_kernel(
    const int* __restrict__ nbr, const float* __restrict__ wh,
    const int* __restrict__ rowptr, int* __restrict__ fillc,
    int* __restrict__ colA, float* __restrict__ wAr)
{
  const int e = blockIdx.x * 256 + threadIdx.x;
  if (e >= N_Q * KNN) return;
  const int i = e / KNN, tt = e % KNN;
  const int j = nbr[e];
  const float w = wh[e];
  int p = rowptr[i] + tt;
  colA[p] = j; wAr[p] = w;
  int q = rowptr[j] + KNN + atomicAdd(&fillc[j], 1);
  colA[q] = i; wAr[q] = w;
}

// ---- coef[i] = lam_i * D_inv_i
__global__ __launch_bounds__(256) void coef_kernel(
    const float* __restrict__ d2min, const float* __restrict__ denom,
    const float* __restrict__ rowsum, float* __restrict__ coefA)
{
  const int i = blockIdx.x * 256 + threadIdx.x;
  if (i < N_Q){
    float lam = expf(-d2min[i] / denom[0]);
    coefA[i] = lam / (rowsum[i] + 1e-8f);
  }
}

// ============ custom grid barrier (sense-reversal, tight spin) ============
__device__ __forceinline__ void gbar_arrive_spin(int* arrive, int* gen){
  int g = __hip_atomic_load(gen, __ATOMIC_RELAXED, __HIP_MEMORY_SCOPE_AGENT);
  if (__hip_atomic_fetch_add(arrive, 1, __ATOMIC_ACQ_REL, __HIP_MEMORY_SCOPE_AGENT) == NBLK - 1){
    __hip_atomic_store(arrive, 0, __ATOMIC_RELAXED, __HIP_MEMORY_SCOPE_AGENT);
    __hip_atomic_fetch_add(gen, 1, __ATOMIC_RELEASE, __HIP_MEMORY_SCOPE_AGENT);
  } else {
    while (__hip_atomic_load(gen, __ATOMIC_RELAXED, __HIP_MEMORY_SCOPE_AGENT) == g)
      __builtin_amdgcn_s_sleep(1);
  }
}

// ---- the while-loop as one cooperative kernel. 64 blocks x 1024 threads,
//      4 rows/wave. Custom barrier; per-block LDS delta reduction; scoped
//      release/acquire fences.
__global__ __launch_bounds__(1024, 4) void mm_loop(
    const float* __restrict__ aM, const float* __restrict__ coefA,
    const int* __restrict__ rowptr, const int* __restrict__ colA,
    const float* __restrict__ wA, float* __restrict__ buf0,
    float* __restrict__ buf1, float* deltas,
    int* arrive, int* gen, int* __restrict__ out)
{
  __shared__ int   sdmax;
  __shared__ float sdelta;
  const int tid  = threadIdx.x;
  const int lane = tid & 63;
  const int wid  = blockIdx.x * 16 + (tid >> 6);
  const int rbase = wid * 4;
  if (tid == 0) sdmax = 0;

  float av[4], cf[4], prev[4], cur[4];
  int p0[4], p1[4];
  #pragma unroll
  for (int u = 0; u < 4; u++){
    const int row = rbase + u;
    av[u] = aM[row * N_C + lane];
    cf[u] = coefA[row];
    p0[u] = rowptr[row]; p1[u] = rowptr[row + 1];
  }

  // y0 = softmax(-a)
  #pragma unroll
  for (int u = 0; u < 4; u++){
    float xv = -av[u];
    float m = wave_max64(xv);
    float e = expf(xv - m);
    float s = wave_sum64(e);
    prev[u] = e / s;
    buf0[(rbase + u) * N_C + lane] = prev[u];
  }
  __builtin_amdgcn_fence(__ATOMIC_RELEASE, "agent");
  __syncthreads();
  if (tid == 0) gbar_arrive_spin(arrive, gen);
  __syncthreads();
  __builtin_amdgcn_fence(__ATOMIC_ACQUIRE, "agent");

  // y1 = step(y0)
  float dmax = 0.f;
  #pragma unroll
  for (int u = 0; u < 4; u++){
    float sp = 0.f;
    for (int p = p0[u]; p < p1[u]; p++) sp = fmaf(wA[p], buf0[colA[p] * N_C + lane], sp);
    float xv = -av[u] + cf[u] * sp;
    float m = wave_max64(xv);
    float e = expf(xv - m);
    float s = wave_sum64(e);
    cur[u] = e / s;
    buf1[(rbase + u) * N_C + lane] = cur[u];
    dmax = fmaxf(dmax, fabsf(cur[u] - prev[u]));
  }
  dmax = wave_max64(dmax);
  if (lane == 0) atomicMax(&sdmax, __float_as_int(dmax));   // LDS atomic, nonneg floats
  __builtin_amdgcn_fence(__ATOMIC_RELEASE, "agent");
  __syncthreads();
  if (tid == 0){
    atomicMax((int*)&deltas[0], sdmax);
    sdmax = 0;
    gbar_arrive_spin(arrive, gen);
    sdelta = __int_as_float(__hip_atomic_load((int*)&deltas[0], __ATOMIC_ACQUIRE, __HIP_MEMORY_SCOPE_AGENT));
  }
  __syncthreads();
  __builtin_amdgcn_fence(__ATOMIC_ACQUIRE, "agent");
  float delta = sdelta;

  int par = 1;                             // buffer currently holding y_new
  for (int t = 0;; t++){
    if (t >= MAX_ITER || delta < EPS_CONV) break;
    const float* src = par ? buf1 : buf0;
    float*       dst = par ? buf0 : buf1;
    dmax = 0.f;
    #pragma unroll
    for (int u = 0; u < 4; u++){
      float sp = 0.f;
      for (int p = p0[u]; p < p1[u]; p++) sp = fmaf(wA[p], src[colA[p] * N_C + lane], sp);
      float xv = -av[u] + cf[u] * sp;
      float m = wave_max64(xv);
      float e = expf(xv - m);
      float s = wave_sum64(e);
      float nxt = e / s;
      dst[(rbase + u) * N_C + lane] = nxt;
      dmax = fmaxf(dmax, fabsf(nxt - cur[u]));
      prev[u] = cur[u]; cur[u] = nxt;
    }
    dmax = wave_max64(dmax);
    if (lane == 0) atomicMax(&sdmax, __float_as_int(dmax));
    __builtin_amdgcn_fence(__ATOMIC_RELEASE, "agent");
    __syncthreads();
    if (tid == 0){
      atomicMax((int*)&deltas[t + 1], sdmax);
      sdmax = 0;
      gbar_arrive_spin(arrive, gen);
      sdelta = __int_as_float(__hip_atomic_load((int*)&deltas[t + 1], __ATOMIC_ACQUIRE, __HIP_MEMORY_SCOPE_AGENT));
    }
    __syncthreads();
    __builtin_amdgcn_fence(__ATOMIC_ACQUIRE, "agent");
    delta = sdelta;
    par ^= 1;
  }

  // argmax of y (prev); first occurrence on ties
  #pragma unroll
  for (int u = 0; u < 4; u++){
    float bv = prev[u]; int bi = lane;
    #pragma unroll
    for (int o = 32; o; o >>= 1){
      float ov = __shfl_xor(bv, o, 64); int oi = __shfl_xor(bi, o, 64);
      if (ov > bv || (ov == bv && oi < bi)){ bv = ov; bi = oi; }
    }
    if (lane == 0) out[rbase + u] = bi;
  }
}

extern "C" void kernel_launch(void* const* d_in, const int* in_sizes, int n_in,
                              void* d_out, int out_size, void* d_ws, size_t ws_size,
                              hipStream_t stream)
{
  const float* feat_s = (const float*)d_in[0];
  const int*   y_s    = (const int*)d_in[1];
  const float* feat_q = (const float*)d_in[2];
  int* out = (int*)d_out;

  char* wp = (char*)d_ws;
  auto alloc = [&](size_t bytes) -> char* {
    char* p = wp;
    wp += (bytes + 255) & ~(size_t)255;
    return p;
  };
  float* Dq     = (float*)alloc((size_t)N_Q * N_Q * 4);      // 64 MB
  float* Pt     = (float*)alloc((size_t)DIM * N_C * 4);
  float* pn     = (float*)alloc(N_C * 4);
  float* qn     = (float*)alloc(N_Q * 4);
  float* aM     = (float*)alloc((size_t)N_Q * N_C * 4);
  float* d2min  = (float*)alloc(N_Q * 4);
  float* denom  = (float*)alloc(256);
  int*   nbr    = (int*)alloc((size_t)N_Q * KNN * 4);
  float* dnbr   = (float*)alloc((size_t)N_Q * KNN * 4);
  float* sigma  = (float*)alloc(N_Q * 4);
  float* wh     = (float*)alloc((size_t)N_Q * KNN * 4);
  float* rowsum = (float*)alloc(N_Q * 4);
  int*   indeg  = (int*)alloc(N_Q * 4);
  int*   rowptr = (int*)alloc((N_Q + 1) * 4);
  int*   fillc  = (int*)alloc(N_Q * 4);
  int*   colA   = (int*)alloc((size_t)2 * N_Q * KNN * 4);
  float* wA     = (float*)alloc((size_t)2 * N_Q * KNN * 4);
  float* buf0   = (float*)alloc((size_t)N_Q * N_C * 4);
  float* buf1   = (float*)alloc((size_t)N_Q * N_C * 4);
  float* deltas = (float*)alloc(64 * 4);
  float* coefA  = (float*)alloc(N_Q * 4);
  int*   syncws = (int*)alloc(256);          // [0]=arrive, [32]=gen (separate lines)

  hipMemsetAsync(rowsum, 0, N_Q * 4, stream);
  hipMemsetAsync(indeg,  0, N_Q * 4, stream);
  hipMemsetAsync(fillc,  0, N_Q * 4, stream);
  hipMemsetAsync(deltas, 0, 64 * 4, stream);
  hipMemsetAsync(syncws, 0, 256, stream);

  proto_kernel  <<<N_C, 256, 0, stream>>>(feat_s, y_s, Pt, pn);
  rownorm_kernel<<<N_Q, 256, 0, stream>>>(feat_q, qn);
  dist_gemm     <<<dim3(N_Q/128, N_Q/128), 256, 0, stream>>>(feat_q, qn, Dq);
  topk_kernel   <<<N_Q, 256, 0, stream>>>(Dq, nbr, dnbr, sigma);
  a_kernel      <<<N_Q, 64, 0, stream>>>(feat_q, Pt, qn, pn, aM, d2min);
  median_kernel <<<1, 1024, 0, stream>>>(d2min, denom);
  wdeg_kernel   <<<(N_Q*KNN + 255)/256, 256, 0, stream>>>(nbr, dnbr, sigma, wh, rowsum, indeg);
  scan_kernel   <<<1, 256, 0, stream>>>(indeg, rowptr);
  fill_kernel   <<<(N_Q*KNN + 255)/256, 256, 0, stream>>>(nbr, wh, rowptr, fillc, colA, wA);
  coef_kernel   <<<(N_Q + 255)/256, 256, 0, stream>>>(d2min, denom, rowsum, coefA);

  int* arrive = &syncws[0];
  int* gen    = &syncws[32];
  void* args[] = {&aM, &coefA, &rowptr, &colA, &wA, &buf0, &buf1, &deltas, &arrive, &gen, &out};
  hipLaunchCooperativeKernel((void*)mm_loop, dim3(NBLK), dim3(1024), args, 0, stream);
}

// Round 6
// 1280.907 us; speedup vs baseline: 6.2174x; 6.2174x over previous
//
#include <hip/hip_runtime.h>
#include <hip/hip_cooperative_groups.h>
#include <cfloat>
#include <cmath>

namespace cg = cooperative_groups;

#define N_Q 4096
#define N_S 1600
#define DIM 1024
#define N_C 64
#define KNN 12
#define MAX_ITER 50
#define EPS_CONV 1e-4f
#define NBLK 256         // mm_loop grid size; must match launch

__device__ __forceinline__ float wave_max64(float v){
  #pragma unroll
  for (int o = 32; o; o >>= 1) v = fmaxf(v, __shfl_xor(v, o, 64));
  return v;
}
__device__ __forceinline__ float wave_sum64(float v){
  #pragma unroll
  for (int o = 32; o; o >>= 1) v += __shfl_xor(v, o, 64);
  return v;
}
__device__ __forceinline__ float wave_min64(float v){
  #pragma unroll
  for (int o = 32; o; o >>= 1) v = fminf(v, __shfl_xor(v, o, 64));
  return v;
}

// ---- prototypes: segment mean over support set, stored TRANSPOSED Pt[f][c];
//      also per-class squared norm pn[c].
__global__ __launch_bounds__(256) void proto_kernel(
    const float* __restrict__ fs, const int* __restrict__ ys,
    float* __restrict__ Pt, float* __restrict__ pn)
{
  const int c = blockIdx.x, t = threadIdx.x;
  float a0 = 0.f, a1 = 0.f, a2 = 0.f, a3 = 0.f;
  int cnt = 0;
  for (int i = 0; i < N_S; i++){
    if (ys[i] == c){
      const float* r = fs + (size_t)i * DIM;
      a0 += r[t]; a1 += r[t + 256]; a2 += r[t + 512]; a3 += r[t + 768];
      cnt++;
    }
  }
  const float inv = 1.0f / fmaxf((float)cnt, 1.0f);
  const float v0 = a0*inv, v1 = a1*inv, v2 = a2*inv, v3 = a3*inv;
  Pt[(t      )*N_C + c] = v0;
  Pt[(t + 256)*N_C + c] = v1;
  Pt[(t + 512)*N_C + c] = v2;
  Pt[(t + 768)*N_C + c] = v3;
  __shared__ float red[256];
  red[t] = v0*v0 + v1*v1 + v2*v2 + v3*v3;
  __syncthreads();
  for (int o = 128; o; o >>= 1){ if (t < o) red[t] += red[t + o]; __syncthreads(); }
  if (t == 0) pn[c] = red[0];
}

// ---- per-row squared norm of feat_q
__global__ __launch_bounds__(256) void rownorm_kernel(
    const float* __restrict__ X, float* __restrict__ qn)
{
  const int i = blockIdx.x, t = threadIdx.x;
  const float* r = X + (size_t)i * DIM;
  float s = r[t]*r[t] + r[t+256]*r[t+256] + r[t+512]*r[t+512] + r[t+768]*r[t+768];
  __shared__ float red[256];
  red[t] = s; __syncthreads();
  for (int o = 128; o; o >>= 1){ if (t < o) red[t] += red[t + o]; __syncthreads(); }
  if (t == 0) qn[i] = red[0];
}

// ---- full pairwise distances: EXACT R2 structure (proven: <=511 us, no
//      spills, 64 MB writes). BK=8, single-buffered LDS, register prefetch,
//      2x2 wave grid / 8x8 lane grid -> LDS fragment reads are 8-distinct-
//      float4 broadcasts (2-way bank alias = free). R5's BK=16 double-buffer
//      spilled to scratch (16 GB WRITE_SIZE) -- do not reintroduce.
__global__ __launch_bounds__(256, 4) void dist_gemm(
    const float* __restrict__ X, const float* __restrict__ qn, float* __restrict__ Dq)
{
  __shared__ float As[8][128];
  __shared__ float Bs[8][128];
  const int t = threadIdx.x;
  const int w = t >> 6, l = t & 63;
  const int ri = (w >> 1) * 64 + (l >> 3) * 8;   // row offset in tile
  const int cj = (w & 1) * 64 + (l & 7) * 8;     // col offset in tile
  const int i0 = blockIdx.y * 128, j0 = blockIdx.x * 128;
  const int lr = t >> 1, lh = (t & 1) * 4;

  const float* pA = X + (size_t)(i0 + lr) * DIM + lh;
  const float* pB = X + (size_t)(j0 + lr) * DIM + lh;

  float acc[8][8];
  #pragma unroll
  for (int u = 0; u < 8; u++)
    #pragma unroll
    for (int v = 0; v < 8; v++) acc[u][v] = 0.f;

  float4 ga = *(const float4*)pA;
  float4 gb = *(const float4*)pB;

  for (int k0 = 0; k0 < DIM; k0 += 8){
    As[lh+0][lr] = ga.x; As[lh+1][lr] = ga.y; As[lh+2][lr] = ga.z; As[lh+3][lr] = ga.w;
    Bs[lh+0][lr] = gb.x; Bs[lh+1][lr] = gb.y; Bs[lh+2][lr] = gb.z; Bs[lh+3][lr] = gb.w;
    __syncthreads();
    if (k0 + 8 < DIM){
      ga = *(const float4*)(pA + k0 + 8);
      gb = *(const float4*)(pB + k0 + 8);
    }
    #pragma unroll
    for (int k = 0; k < 8; k++){
      float4 a0 = *(const float4*)&As[k][ri];
      float4 a1 = *(const float4*)&As[k][ri + 4];
      float4 b0 = *(const float4*)&Bs[k][cj];
      float4 b1 = *(const float4*)&Bs[k][cj + 4];
      float a[8] = {a0.x,a0.y,a0.z,a0.w,a1.x,a1.y,a1.z,a1.w};
      float b[8] = {b0.x,b0.y,b0.z,b0.w,b1.x,b1.y,b1.z,b1.w};
      #pragma unroll
      for (int u = 0; u < 8; u++)
        #pragma unroll
        for (int v = 0; v < 8; v++) acc[u][v] = fmaf(a[u], b[v], acc[u][v]);
    }
    __syncthreads();
  }

  const float4 qj0 = *(const float4*)&qn[j0 + cj];
  const float4 qj1 = *(const float4*)&qn[j0 + cj + 4];
  const float qj[8] = {qj0.x,qj0.y,qj0.z,qj0.w,qj1.x,qj1.y,qj1.z,qj1.w};
  #pragma unroll
  for (int u = 0; u < 8; u++){
    const int i = i0 + ri + u;
    const float qi = qn[i];
    float o[8];
    #pragma unroll
    for (int v = 0; v < 8; v++)
      o[v] = sqrtf(fmaxf(qi + qj[v] - 2.0f * acc[u][v], 0.f));
    float* dst = &Dq[(size_t)i * N_Q + j0 + cj];
    *(float4*)(dst    ) = make_float4(o[0],o[1],o[2],o[3]);
    *(float4*)(dst + 4) = make_float4(o[4],o[5],o[6],o[7]);
  }
}

// ---- per-row 13 smallest (ties -> smaller index). Row cached in REGISTERS
//      (16 per thread); shfl wave-reduce; 2 syncthreads per pass.
__global__ __launch_bounds__(256) void topk_kernel(
    const float* __restrict__ Dq, int* __restrict__ nbr,
    float* __restrict__ dnbr, float* __restrict__ sigma)
{
  const int i = blockIdx.x, t = threadIdx.x;
  const float* row = Dq + (size_t)i * N_Q;
  float r[16];
  #pragma unroll
  for (int u = 0; u < 16; u++) r[u] = row[t + u * 256];

  __shared__ float pvf[4];
  __shared__ int   pif[4];
  __shared__ int   bwi_s;

  for (int s = 0; s < KNN + 1; s++){
    float best = FLT_MAX; int bj = 0x7fffffff;
    #pragma unroll
    for (int u = 0; u < 16; u++){
      float v = r[u];
      if (v < best){ best = v; bj = t + u * 256; }   // ascending j: strict < keeps earliest
    }
    #pragma unroll
    for (int o = 32; o; o >>= 1){
      float ov = __shfl_xor(best, o, 64); int oj = __shfl_xor(bj, o, 64);
      if (ov < best || (ov == best && oj < bj)){ best = ov; bj = oj; }
    }
    if ((t & 63) == 0){ pvf[t >> 6] = best; pif[t >> 6] = bj; }
    __syncthreads();
    if (t == 0){
      float bv = pvf[0]; int bi2 = pif[0];
      #pragma unroll
      for (int w2 = 1; w2 < 4; w2++){
        float v2 = pvf[w2]; int i2 = pif[w2];
        if (v2 < bv || (v2 == bv && i2 < bi2)){ bv = v2; bi2 = i2; }
      }
      bwi_s = bi2;
      if (s >= 1){ nbr[i*KNN + s - 1] = bi2; dnbr[i*KNN + s - 1] = bv; }
      if (s == KNN) sigma[i] = bv + 1e-8f;
    }
    __syncthreads();
    const int widx = bwi_s;
    if ((widx & 255) == t) r[widx >> 8] = FLT_MAX;   // owner invalidates (registers)
  }
}

// ---- a[i][c] = clamped sqdist(query i, proto c); d2min[i] = min_c a[i][c]
__global__ __launch_bounds__(64) void a_kernel(
    const float* __restrict__ Xq, const float* __restrict__ Pt,
    const float* __restrict__ qn, const float* __restrict__ pn,
    float* __restrict__ aM, float* __restrict__ d2min)
{
  const int i = blockIdx.x, c = threadIdx.x;
  __shared__ float x[DIM];
  const float* r = Xq + (size_t)i * DIM;
  for (int f = c; f < DIM; f += 64) x[f] = r[f];
  __syncthreads();
  float dot = 0.f;
  #pragma unroll 4
  for (int f = 0; f < DIM; f++) dot = fmaf(x[f], Pt[f*N_C + c], dot);
  float d2 = fmaxf(qn[i] + pn[c] - 2.0f * dot, 0.0f);
  aM[i*N_C + c] = d2;
  float m = wave_min64(d2);
  if (c == 0) d2min[i] = m;
}

// ---- median of d = sqrt(d2min) via single-block bitonic sort of 4096
__global__ __launch_bounds__(1024) void median_kernel(
    const float* __restrict__ d2min, float* __restrict__ denom)
{
  __shared__ float s[N_Q];
  const int t = threadIdx.x;
  for (int j = t; j < N_Q; j += 1024) s[j] = sqrtf(d2min[j]);
  __syncthreads();
  for (int ksz = 2; ksz <= N_Q; ksz <<= 1){
    for (int st = ksz >> 1; st > 0; st >>= 1){
      for (int i = t; i < N_Q; i += 1024){
        int j = i ^ st;
        if (j > i){
          float a = s[i], b = s[j];
          bool up = ((i & ksz) == 0);
          if (up ? (a > b) : (a < b)){ s[i] = b; s[j] = a; }
        }
      }
      __syncthreads();
    }
  }
  if (t == 0){
    float med = 0.5f * (s[N_Q/2 - 1] + s[N_Q/2]);
    denom[0] = 2.0f * med * med + 1e-8f;
  }
}

// ---- halved edge weights, symmetric row sums, in-degree counts
__global__ __launch_bounds__(256) void wdeg_kernel(
    const int* __restrict__ nbr, const float* __restrict__ dnbr,
    const float* __restrict__ sigma, float* __restrict__ wh,
    float* __restrict__ rowsum, int* __restrict__ indeg)
{
  const int e = blockIdx.x * 256 + threadIdx.x;
  if (e >= N_Q * KNN) return;
  const int i = e / KNN;
  const int j = nbr[e];
  float w = 0.5f * expf(-dnbr[e] / (sigma[i] * sigma[j]));
  wh[e] = w;
  atomicAdd(&rowsum[i], w);
  atomicAdd(&rowsum[j], w);
  atomicAdd(&indeg[j], 1);
}

// ---- CSR row pointers: deg[r] = 12 (out) + indeg[r] (in)
__global__ __launch_bounds__(256) void scan_kernel(
    const int* __restrict__ indeg, int* __restrict__ rowptr)
{
  __shared__ int part[256];
  const int t = threadIdx.x;
  const int base = t * 16;
  int loc[16];
  int lsum = 0;
  for (int u = 0; u < 16; u++){ loc[u] = lsum; lsum += indeg[base + u]; }
  part[t] = lsum; __syncthreads();
  if (t == 0){
    int run = 0;
    for (int q = 0; q < 256; q++){ int v = part[q]; part[q] = run; run += v; }
  }
  __syncthreads();
  const int off = part[t];
  for (int u = 0; u < 16; u++){
    int r = base + u;
    rowptr[r] = KNN * r + off + loc[u];
  }
  if (t == 255) rowptr[N_Q] = KNN * N_Q + off + lsum;
}

// ---- CSR fill: out-edges in fixed slots, in-edges via per-row atomic cursor.
//      colA stores the column PREMULTIPLIED by 64 (row byte-stride in y),
//      saving a v_mul per gather in the hot mm_loop.
__global__ __launch_bounds__(256) void fill_kernel(
    const int* __restrict__ nbr, const float* __restrict__ wh,
    const int* __restrict__ rowptr, int* __restrict__ fillc,
    int* __restrict__ colA, float* __restrict__ wAr)
{
  const int e = blockIdx.x * 256 + threadIdx.x;
  if (e >= N_Q * KNN) return;
  const int i = e / KNN, tt = e % KNN;
  const int j = nbr[e];
  const float w = wh[e];
  int p = rowptr[i] + tt;
  colA[p] = j * N_C; wAr[p] = w;
  int q = rowptr[j] + KNN + atomicAdd(&fillc[j], 1);
  colA[q] = i * N_C; wAr[q] = w;
}

// ---- coef[i] = lam_i * D_inv_i
__global__ __launch_bounds__(256) void coef_kernel(
    const float* __restrict__ d2min, const float* __restrict__ denom,
    const float* __restrict__ rowsum, float* __restrict__ coefA)
{
  const int i = blockIdx.x * 256 + threadIdx.x;
  if (i < N_Q){
    float lam = expf(-d2min[i] / denom[0]);
    coefA[i] = lam / (rowsum[i] + 1e-8f);
  }
}

// ============ custom grid barrier (sense-reversal, tight spin) ============
__device__ __forceinline__ void gbar_arrive_spin(int* arrive, int* gen){
  int g = __hip_atomic_load(gen, __ATOMIC_RELAXED, __HIP_MEMORY_SCOPE_AGENT);
  if (__hip_atomic_fetch_add(arrive, 1, __ATOMIC_ACQ_REL, __HIP_MEMORY_SCOPE_AGENT) == NBLK - 1){
    __hip_atomic_store(arrive, 0, __ATOMIC_RELAXED, __HIP_MEMORY_SCOPE_AGENT);
    __hip_atomic_fetch_add(gen, 1, __ATOMIC_RELEASE, __HIP_MEMORY_SCOPE_AGENT);
  } else {
    while (__hip_atomic_load(gen, __ATOMIC_RELAXED, __HIP_MEMORY_SCOPE_AGENT) == g)
      __builtin_amdgcn_s_sleep(1);
  }
}

// ---- the while-loop as one cooperative kernel. 256 blocks x 1024 threads,
//      ONE row per wave: all 256 CUs' load pipes active (R2/R4 ran on only
//      64 CUs -> gather-latency-bound at ~10us/iter), 16 independent row
//      chains per CU, and a 4-way ILP split in the SpMV gather (reassociation
//      safe: CSR order already differs from the dense reference).
__global__ __launch_bounds__(1024) void mm_loop(
    const float* __restrict__ aM, const float* __restrict__ coefA,
    const int* __restrict__ rowptr, const int* __restrict__ colA,
    const float* __restrict__ wA, float* __restrict__ buf0,
    float* __restrict__ buf1, float* deltas,
    int* arrive, int* gen, int* __restrict__ out)
{
  __shared__ int   sdmax;
  __shared__ float sdelta;
  const int tid  = threadIdx.x;
  const int lane = tid & 63;
  const int row  = blockIdx.x * 16 + (tid >> 6);
  if (tid == 0) sdmax = 0;

  const float av = aM[row * N_C + lane];
  const float cf = coefA[row];
  const int p0 = rowptr[row], p1 = rowptr[row + 1];

  // y0 = softmax(-a)
  float xv = -av;
  float m = wave_max64(xv);
  float e = expf(xv - m);
  float s = wave_sum64(e);
  float prev = e / s;
  buf0[row * N_C + lane] = prev;
  __builtin_amdgcn_fence(__ATOMIC_RELEASE, "agent");
  __syncthreads();
  if (tid == 0) gbar_arrive_spin(arrive, gen);
  __syncthreads();
  __builtin_amdgcn_fence(__ATOMIC_ACQUIRE, "agent");

  // y1 = step(y0)
  {
    float s0 = 0.f, s1 = 0.f, s2 = 0.f, s3 = 0.f;
    int p = p0;
    for (; p + 4 <= p1; p += 4){
      s0 = fmaf(wA[p    ], buf0[colA[p    ] + lane], s0);
      s1 = fmaf(wA[p + 1], buf0[colA[p + 1] + lane], s1);
      s2 = fmaf(wA[p + 2], buf0[colA[p + 2] + lane], s2);
      s3 = fmaf(wA[p + 3], buf0[colA[p + 3] + lane], s3);
    }
    for (; p < p1; p++) s0 = fmaf(wA[p], buf0[colA[p] + lane], s0);
    xv = -av + cf * ((s0 + s1) + (s2 + s3));
  }
  m = wave_max64(xv); e = expf(xv - m); s = wave_sum64(e);
  float cur = e / s;
  buf1[row * N_C + lane] = cur;
  float dmax = wave_max64(fabsf(cur - prev));
  if (lane == 0) atomicMax(&sdmax, __float_as_int(dmax));   // LDS atomic, nonneg floats
  __builtin_amdgcn_fence(__ATOMIC_RELEASE, "agent");
  __syncthreads();
  if (tid == 0){
    atomicMax((int*)&deltas[0], sdmax);
    sdmax = 0;
    gbar_arrive_spin(arrive, gen);
    sdelta = __int_as_float(__hip_atomic_load((int*)&deltas[0], __ATOMIC_ACQUIRE, __HIP_MEMORY_SCOPE_AGENT));
  }
  __syncthreads();
  __builtin_amdgcn_fence(__ATOMIC_ACQUIRE, "agent");
  float delta = sdelta;

  int par = 1;                             // buffer currently holding y_new
  for (int t = 0;; t++){
    if (t >= MAX_ITER || delta < EPS_CONV) break;
    const float* src = par ? buf1 : buf0;
    float*       dst = par ? buf0 : buf1;
    float s0 = 0.f, s1 = 0.f, s2 = 0.f, s3 = 0.f;
    int p = p0;
    for (; p + 4 <= p1; p += 4){
      s0 = fmaf(wA[p    ], src[colA[p    ] + lane], s0);
      s1 = fmaf(wA[p + 1], src[colA[p + 1] + lane], s1);
      s2 = fmaf(wA[p + 2], src[colA[p + 2] + lane], s2);
      s3 = fmaf(wA[p + 3], src[colA[p + 3] + lane], s3);
    }
    for (; p < p1; p++) s0 = fmaf(wA[p], src[colA[p] + lane], s0);
    xv = -av + cf * ((s0 + s1) + (s2 + s3));
    m = wave_max64(xv); e = expf(xv - m); s = wave_sum64(e);
    float nxt = e / s;
    dst[row * N_C + lane] = nxt;
    dmax = wave_max64(fabsf(nxt - cur));
    prev = cur; cur = nxt;
    if (lane == 0) atomicMax(&sdmax, __float_as_int(dmax));
    __builtin_amdgcn_fence(__ATOMIC_RELEASE, "agent");
    __syncthreads();
    if (tid == 0){
      atomicMax((int*)&deltas[t + 1], sdmax);
      sdmax = 0;
      gbar_arrive_spin(arrive, gen);
      sdelta = __int_as_float(__hip_atomic_load((int*)&deltas[t + 1], __ATOMIC_ACQUIRE, __HIP_MEMORY_SCOPE_AGENT));
    }
    __syncthreads();
    __builtin_amdgcn_fence(__ATOMIC_ACQUIRE, "agent");
    delta = sdelta;
    par ^= 1;
  }

  // argmax of y (prev); first occurrence on ties
  float bv = prev; int bi = lane;
  #pragma unroll
  for (int o = 32; o; o >>= 1){
    float ov = __shfl_xor(bv, o, 64); int oi = __shfl_xor(bi, o, 64);
    if (ov > bv || (ov == bv && oi < bi)){ bv = ov; bi = oi; }
  }
  if (lane == 0) out[row] = bi;
}

extern "C" void kernel_launch(void* const* d_in, const int* in_sizes, int n_in,
                              void* d_out, int out_size, void* d_ws, size_t ws_size,
                              hipStream_t stream)
{
  const float* feat_s = (const float*)d_in[0];
  const int*   y_s    = (const int*)d_in[1];
  const float* feat_q = (const float*)d_in[2];
  int* out = (int*)d_out;

  char* wp = (char*)d_ws;
  auto alloc = [&](size_t bytes) -> char* {
    char* p = wp;
    wp += (bytes + 255) & ~(size_t)255;
    return p;
  };
  float* Dq     = (float*)alloc((size_t)N_Q * N_Q * 4);      // 64 MB
  float* Pt     = (float*)alloc((size_t)DIM * N_C * 4);
  float* pn     = (float*)alloc(N_C * 4);
  float* qn     = (float*)alloc(N_Q * 4);
  float* aM     = (float*)alloc((size_t)N_Q * N_C * 4);
  float* d2min  = (float*)alloc(N_Q * 4);
  float* denom  = (float*)alloc(256);
  int*   nbr    = (int*)alloc((size_t)N_Q * KNN * 4);
  float* dnbr   = (float*)alloc((size_t)N_Q * KNN * 4);
  float* sigma  = (float*)alloc(N_Q * 4);
  float* wh     = (float*)alloc((size_t)N_Q * KNN * 4);
  float* rowsum = (float*)alloc(N_Q * 4);
  int*   indeg  = (int*)alloc(N_Q * 4);
  int*   rowptr = (int*)alloc((N_Q + 1) * 4);
  int*   fillc  = (int*)alloc(N_Q * 4);
  int*   colA   = (int*)alloc((size_t)2 * N_Q * KNN * 4);
  float* wA     = (float*)alloc((size_t)2 * N_Q * KNN * 4);
  float* buf0   = (float*)alloc((size_t)N_Q * N_C * 4);
  float* buf1   = (float*)alloc((size_t)N_Q * N_C * 4);
  float* deltas = (float*)alloc(64 * 4);
  float* coefA  = (float*)alloc(N_Q * 4);
  int*   syncws = (int*)alloc(256);          // [0]=arrive, [32]=gen (separate lines)

  hipMemsetAsync(rowsum, 0, N_Q * 4, stream);
  hipMemsetAsync(indeg,  0, N_Q * 4, stream);
  hipMemsetAsync(fillc,  0, N_Q * 4, stream);
  hipMemsetAsync(deltas, 0, 64 * 4, stream);
  hipMemsetAsync(syncws, 0, 256, stream);

  proto_kernel  <<<N_C, 256, 0, stream>>>(feat_s, y_s, Pt, pn);
  rownorm_kernel<<<N_Q, 256, 0, stream>>>(feat_q, qn);
  dist_gemm     <<<dim3(N_Q/128, N_Q/128), 256, 0, stream>>>(feat_q, qn, Dq);
  topk_kernel   <<<N_Q, 256, 0, stream>>>(Dq, nbr, dnbr, sigma);
  a_kernel      <<<N_Q, 64, 0, stream>>>(feat_q, Pt, qn, pn, aM, d2min);
  median_kernel <<<1, 1024, 0, stream>>>(d2min, denom);
  wdeg_kernel   <<<(N_Q*KNN + 255)/256, 256, 0, stream>>>(nbr, dnbr, sigma, wh, rowsum, indeg);
  scan_kernel   <<<1, 256, 0, stream>>>(indeg, rowptr);
  fill_kernel   <<<(N_Q*KNN + 255)/256, 256, 0, stream>>>(nbr, wh, rowptr, fillc, colA, wA);
  coef_kernel   <<<(N_Q + 255)/256, 256, 0, stream>>>(d2min, denom, rowsum, coefA);

  int* arrive = &syncws[0];
  int* gen    = &syncws[32];
  void* args[] = {&aM, &coefA, &rowptr, &colA, &wA, &buf0, &buf1, &deltas, &arrive, &gen, &out};
  hipLaunchCooperativeKernel((void*)mm_loop, dim3(NBLK), dim3(1024), args, 0, stream);
}

// Round 7
// 953.060 us; speedup vs baseline: 8.3562x; 1.3440x over previous
//
#include <hip/hip_runtime.h>
#include <hip/hip_cooperative_groups.h>
#include <cfloat>
#include <cmath>

#define N_Q 4096
#define N_S 1600
#define DIM 1024
#define N_C 64
#define KNN 12
#define MAX_ITER 50
#define EPS_CONV 1e-4f
#define NBLK 256         // tail_loop grid size (16 groups x 16 blocks)

__device__ __forceinline__ float wave_max64(float v){
  #pragma unroll
  for (int o = 32; o; o >>= 1) v = fmaxf(v, __shfl_xor(v, o, 64));
  return v;
}
__device__ __forceinline__ float wave_sum64(float v){
  #pragma unroll
  for (int o = 32; o; o >>= 1) v += __shfl_xor(v, o, 64);
  return v;
}
__device__ __forceinline__ float wave_min64(float v){
  #pragma unroll
  for (int o = 32; o; o >>= 1) v = fminf(v, __shfl_xor(v, o, 64));
  return v;
}

// coherent (device-visible) element accesses: bypass stale per-XCD L2 on load,
// write through to the coherence point on store. Used ONLY for cross-block-
// communicated data inside tail_loop; read-only data keeps plain cached loads.
__device__ __forceinline__ float aload(const float* p){
  return __hip_atomic_load(p, __ATOMIC_RELAXED, __HIP_MEMORY_SCOPE_AGENT);
}
__device__ __forceinline__ void astore(float* p, float v){
  __hip_atomic_store(p, v, __ATOMIC_RELAXED, __HIP_MEMORY_SCOPE_AGENT);
}
__device__ __forceinline__ int aloadi(const int* p){
  return __hip_atomic_load(p, __ATOMIC_RELAXED, __HIP_MEMORY_SCOPE_AGENT);
}
__device__ __forceinline__ void astorei(int* p, int v){
  __hip_atomic_store(p, v, __ATOMIC_RELAXED, __HIP_MEMORY_SCOPE_AGENT);
}

// ---- prototypes: segment mean, stored TRANSPOSED Pt[f][c]; per-class sqnorm.
__global__ __launch_bounds__(256) void proto_kernel(
    const float* __restrict__ fs, const int* __restrict__ ys,
    float* __restrict__ Pt, float* __restrict__ pn)
{
  const int c = blockIdx.x, t = threadIdx.x;
  float a0 = 0.f, a1 = 0.f, a2 = 0.f, a3 = 0.f;
  int cnt = 0;
  for (int i = 0; i < N_S; i++){
    if (ys[i] == c){
      const float* r = fs + (size_t)i * DIM;
      a0 += r[t]; a1 += r[t + 256]; a2 += r[t + 512]; a3 += r[t + 768];
      cnt++;
    }
  }
  const float inv = 1.0f / fmaxf((float)cnt, 1.0f);
  const float v0 = a0*inv, v1 = a1*inv, v2 = a2*inv, v3 = a3*inv;
  Pt[(t      )*N_C + c] = v0;
  Pt[(t + 256)*N_C + c] = v1;
  Pt[(t + 512)*N_C + c] = v2;
  Pt[(t + 768)*N_C + c] = v3;
  __shared__ float red[256];
  red[t] = v0*v0 + v1*v1 + v2*v2 + v3*v3;
  __syncthreads();
  for (int o = 128; o; o >>= 1){ if (t < o) red[t] += red[t + o]; __syncthreads(); }
  if (t == 0) pn[c] = red[0];
}

// ---- per-row squared norm of feat_q
__global__ __launch_bounds__(256) void rownorm_kernel(
    const float* __restrict__ X, float* __restrict__ qn)
{
  const int i = blockIdx.x, t = threadIdx.x;
  const float* r = X + (size_t)i * DIM;
  float s = r[t]*r[t] + r[t+256]*r[t+256] + r[t+512]*r[t+512] + r[t+768]*r[t+768];
  __shared__ float red[256];
  red[t] = s; __syncthreads();
  for (int o = 128; o; o >>= 1){ if (t < o) red[t] += red[t + o]; __syncthreads(); }
  if (t == 0) qn[i] = red[0];
}

// ---- full pairwise distances (proven R2/R6 shape: 442 us, 64 MB writes,
//      VALUBusy 71%). BK=8 single-buffer, register prefetch. Do NOT change
//      to BK=16 dbuf (R5: scratch spill, 16 GB writes) or triangular+mirror
//      (R3/R4: 46x write amplification).
__global__ __launch_bounds__(256, 4) void dist_gemm(
    const float* __restrict__ X, const float* __restrict__ qn, float* __restrict__ Dq)
{
  __shared__ float As[8][128];
  __shared__ float Bs[8][128];
  const int t = threadIdx.x;
  const int w = t >> 6, l = t & 63;
  const int ri = (w >> 1) * 64 + (l >> 3) * 8;
  const int cj = (w & 1) * 64 + (l & 7) * 8;
  const int i0 = blockIdx.y * 128, j0 = blockIdx.x * 128;
  const int lr = t >> 1, lh = (t & 1) * 4;

  const float* pA = X + (size_t)(i0 + lr) * DIM + lh;
  const float* pB = X + (size_t)(j0 + lr) * DIM + lh;

  float acc[8][8];
  #pragma unroll
  for (int u = 0; u < 8; u++)
    #pragma unroll
    for (int v = 0; v < 8; v++) acc[u][v] = 0.f;

  float4 ga = *(const float4*)pA;
  float4 gb = *(const float4*)pB;

  for (int k0 = 0; k0 < DIM; k0 += 8){
    As[lh+0][lr] = ga.x; As[lh+1][lr] = ga.y; As[lh+2][lr] = ga.z; As[lh+3][lr] = ga.w;
    Bs[lh+0][lr] = gb.x; Bs[lh+1][lr] = gb.y; Bs[lh+2][lr] = gb.z; Bs[lh+3][lr] = gb.w;
    __syncthreads();
    if (k0 + 8 < DIM){
      ga = *(const float4*)(pA + k0 + 8);
      gb = *(const float4*)(pB + k0 + 8);
    }
    #pragma unroll
    for (int k = 0; k < 8; k++){
      float4 a0 = *(const float4*)&As[k][ri];
      float4 a1 = *(const float4*)&As[k][ri + 4];
      float4 b0 = *(const float4*)&Bs[k][cj];
      float4 b1 = *(const float4*)&Bs[k][cj + 4];
      float a[8] = {a0.x,a0.y,a0.z,a0.w,a1.x,a1.y,a1.z,a1.w};
      float b[8] = {b0.x,b0.y,b0.z,b0.w,b1.x,b1.y,b1.z,b1.w};
      #pragma unroll
      for (int u = 0; u < 8; u++)
        #pragma unroll
        for (int v = 0; v < 8; v++) acc[u][v] = fmaf(a[u], b[v], acc[u][v]);
    }
    __syncthreads();
  }

  const float4 qj0 = *(const float4*)&qn[j0 + cj];
  const float4 qj1 = *(const float4*)&qn[j0 + cj + 4];
  const float qj[8] = {qj0.x,qj0.y,qj0.z,qj0.w,qj1.x,qj1.y,qj1.z,qj1.w};
  #pragma unroll
  for (int u = 0; u < 8; u++){
    const int i = i0 + ri + u;
    const float qi = qn[i];
    float o[8];
    #pragma unroll
    for (int v = 0; v < 8; v++)
      o[v] = sqrtf(fmaxf(qi + qj[v] - 2.0f * acc[u][v], 0.f));
    float* dst = &Dq[(size_t)i * N_Q + j0 + cj];
    *(float4*)(dst    ) = make_float4(o[0],o[1],o[2],o[3]);
    *(float4*)(dst + 4) = make_float4(o[4],o[5],o[6],o[7]);
  }
}

// ---- per-row 13 smallest (ties -> smaller index), row in registers.
__global__ __launch_bounds__(256) void topk_kernel(
    const float* __restrict__ Dq, int* __restrict__ nbr,
    float* __restrict__ dnbr, float* __restrict__ sigma)
{
  const int i = blockIdx.x, t = threadIdx.x;
  const float* row = Dq + (size_t)i * N_Q;
  float r[16];
  #pragma unroll
  for (int u = 0; u < 16; u++) r[u] = row[t + u * 256];

  __shared__ float pvf[4];
  __shared__ int   pif[4];
  __shared__ int   bwi_s;

  for (int s = 0; s < KNN + 1; s++){
    float best = FLT_MAX; int bj = 0x7fffffff;
    #pragma unroll
    for (int u = 0; u < 16; u++){
      float v = r[u];
      if (v < best){ best = v; bj = t + u * 256; }
    }
    #pragma unroll
    for (int o = 32; o; o >>= 1){
      float ov = __shfl_xor(best, o, 64); int oj = __shfl_xor(bj, o, 64);
      if (ov < best || (ov == best && oj < bj)){ best = ov; bj = oj; }
    }
    if ((t & 63) == 0){ pvf[t >> 6] = best; pif[t >> 6] = bj; }
    __syncthreads();
    if (t == 0){
      float bv = pvf[0]; int bi2 = pif[0];
      #pragma unroll
      for (int w2 = 1; w2 < 4; w2++){
        float v2 = pvf[w2]; int i2 = pif[w2];
        if (v2 < bv || (v2 == bv && i2 < bi2)){ bv = v2; bi2 = i2; }
      }
      bwi_s = bi2;
      if (s >= 1){ nbr[i*KNN + s - 1] = bi2; dnbr[i*KNN + s - 1] = bv; }
      if (s == KNN) sigma[i] = bv + 1e-8f;
    }
    __syncthreads();
    const int widx = bwi_s;
    if ((widx & 255) == t) r[widx >> 8] = FLT_MAX;
  }
}

// ============ hierarchical monotonic grid barrier (leader-only) ============
// 16 groups x 16 blocks; group counters on separate 128B lines; counters are
// monotonic (no reset races). No release/acquire decoration: data visibility
// is handled by coherent y accesses + the __syncthreads vmem drain.
__device__ __forceinline__ void gbar_leader(int* garr, int* gcnt, int* gen, int target){
  const int g = blockIdx.x >> 4;
  int old = __hip_atomic_fetch_add(&garr[g * 32], 1, __ATOMIC_RELAXED, __HIP_MEMORY_SCOPE_AGENT);
  if ((old & 15) == 15){
    int o2 = __hip_atomic_fetch_add(gcnt, 1, __ATOMIC_RELAXED, __HIP_MEMORY_SCOPE_AGENT);
    if ((o2 & 15) == 15)
      __hip_atomic_fetch_add(gen, 1, __ATOMIC_RELAXED, __HIP_MEMORY_SCOPE_AGENT);
  }
  while (__hip_atomic_load(gen, __ATOMIC_RELAXED, __HIP_MEMORY_SCOPE_AGENT) < target)
    __builtin_amdgcn_s_sleep(1);
}

// ---- fused tail: a-matrix (in registers), wdeg, {scan | median | y0},
//      fill+coef, then the full while-loop. 256 blocks x 1024 threads,
//      one row per wave. Barrier-separated phases; ONE fence pair total
//      (after graph build) so colA/wA/rowptr stay plain-cached in the loop.
__global__ __launch_bounds__(1024, 4) void tail_loop(
    const float* __restrict__ Xq, const float* __restrict__ Pt,
    const float* __restrict__ pn, const float* __restrict__ qn,
    const int* __restrict__ nbr, const float* __restrict__ dnbr,
    const float* __restrict__ sigma,
    float* d2min, float* denom, float* wh,
    float* rowsum, int* indeg, int* rowptr, int* fillc,
    int* colA, float* wA, float* buf0, float* buf1, float* deltas,
    int* gcnt, int* gen, int* garr, int* __restrict__ out)
{
  __shared__ int   sdmax;
  __shared__ float sdelta;
  __shared__ int   ipart[1024];
  __shared__ int   hist[1024];
  __shared__ float cand[4096];
  __shared__ int   candn, b1s, b2s;

  const int tid  = threadIdx.x;
  const int lane = tid & 63;
  const int wv   = tid >> 6;
  const int row  = blockIdx.x * 16 + wv;
  int barno = 0;
  if (tid == 0) sdmax = 0;

  // ---------- P0a: a-row (kept in registers; no aM buffer) ----------
  const float* xr = Xq + (size_t)row * DIM;
  float dp[8];
  #pragma unroll
  for (int u = 0; u < 8; u++) dp[u] = 0.f;
  for (int f = 0; f < DIM; f += 8){
    #pragma unroll
    for (int u = 0; u < 8; u++)
      dp[u] = fmaf(xr[f + u], Pt[(f + u) * N_C + lane], dp[u]);
  }
  const float dot = ((dp[0]+dp[1])+(dp[2]+dp[3])) + ((dp[4]+dp[5])+(dp[6]+dp[7]));
  const float av  = fmaxf(qn[row] + pn[lane] - 2.0f * dot, 0.0f);
  const float d2m = wave_min64(av);
  if (lane == 0) astore(&d2min[row], d2m);

  // ---------- P0b: edge weights + degrees (1 edge per thread) ----------
  const int e = blockIdx.x * 1024 + tid;
  if (e < N_Q * KNN){
    const int i = e / KNN;
    const int j = nbr[e];
    float wgt = 0.5f * expf(-dnbr[e] / (sigma[i] * sigma[j]));
    astore(&wh[e], wgt);
    atomicAdd(&rowsum[i], wgt);
    atomicAdd(&rowsum[j], wgt);
    atomicAdd(&indeg[j], 1);
  }

  barno++; __syncthreads();
  if (tid == 0) gbar_leader(garr, gcnt, gen, barno);
  __syncthreads();

  // ---------- P1: y0 (all blocks) + scan (block 0) + median (block 1) ----------
  float xv = -av;
  float m = wave_max64(xv), ee = expf(xv - m), ss = wave_sum64(ee);
  float prev = ee / ss;
  astore(&buf0[row * N_C + lane], prev);

  if (blockIdx.x == 0){
    // rowptr prefix scan over indeg (4 values/thread, Hillis-Steele)
    const int base = tid * 4;
    int c0 = aloadi(&indeg[base]),     c1 = aloadi(&indeg[base + 1]);
    int c2 = aloadi(&indeg[base + 2]), c3 = aloadi(&indeg[base + 3]);
    const int s4 = c0 + c1 + c2 + c3;
    ipart[tid] = s4;
    __syncthreads();
    for (int off = 1; off < 1024; off <<= 1){
      int v = (tid >= off) ? ipart[tid - off] : 0;
      __syncthreads();
      ipart[tid] += v;
      __syncthreads();
    }
    int run = ipart[tid] - s4;   // exclusive prefix
    astorei(&rowptr[base    ], KNN * (base    ) + run); run += c0;
    astorei(&rowptr[base + 1], KNN * (base + 1) + run); run += c1;
    astorei(&rowptr[base + 2], KNN * (base + 2) + run); run += c2;
    astorei(&rowptr[base + 3], KNN * (base + 3) + run);
    if (tid == 1023) astorei(&rowptr[N_Q], KNN * N_Q + ipart[1023]);
  }
  if (blockIdx.x == 1){
    // exact median of d=sqrt(d2min) via histogram selection (replaces the
    // ~25us single-block bitonic sort of 4096)
    const int base = tid * 4;
    float dv[4];
    #pragma unroll
    for (int u = 0; u < 4; u++) dv[u] = sqrtf(aload(&d2min[base + u]));
    float mn = fminf(fminf(dv[0], dv[1]), fminf(dv[2], dv[3]));
    float mx = fmaxf(fmaxf(dv[0], dv[1]), fmaxf(dv[2], dv[3]));
    mn = wave_min64(mn); mx = wave_max64(mx);
    if (lane == 0){ cand[wv] = mn; cand[wv + 16] = mx; }
    __syncthreads();
    if (tid == 0){
      float a = cand[0], b = cand[16];
      for (int k = 1; k < 16; k++){ a = fminf(a, cand[k]); b = fmaxf(b, cand[16 + k]); }
      cand[32] = a; cand[33] = b;
    }
    __syncthreads();
    mn = cand[32]; mx = cand[33];
    const float rng = mx - mn;
    const float scale = (rng > 0.f) ? (1024.0f / rng) : 0.f;
    hist[tid] = 0;
    __syncthreads();
    int bidx[4];
    #pragma unroll
    for (int u = 0; u < 4; u++){
      int b = (int)((dv[u] - mn) * scale);
      b = b < 0 ? 0 : (b > 1023 ? 1023 : b);
      bidx[u] = b;
      atomicAdd(&hist[b], 1);
    }
    __syncthreads();
    for (int off = 1; off < 1024; off <<= 1){        // inclusive prefix
      int v = (tid >= off) ? hist[tid - off] : 0;
      __syncthreads();
      hist[tid] += v;
      __syncthreads();
    }
    if (hist[tid] >= 2048 && (tid == 0 || hist[tid - 1] < 2048)) b1s = tid;
    if (hist[tid] >= 2049 && (tid == 0 || hist[tid - 1] < 2049)) b2s = tid;
    if (tid == 0) candn = 0;
    __syncthreads();
    const int b1 = b1s, b2 = b2s;
    const int cntBefore = (b1 > 0) ? hist[b1 - 1] : 0;
    #pragma unroll
    for (int u = 0; u < 4; u++){
      if (bidx[u] >= b1 && bidx[u] <= b2){
        int pos = atomicAdd(&candn, 1);
        cand[pos] = dv[u];
      }
    }
    __syncthreads();
    const int mcnt = candn;
    int P = 2; while (P < mcnt) P <<= 1;
    for (int i2 = mcnt + tid; i2 < P; i2 += 1024) cand[i2] = FLT_MAX;
    __syncthreads();
    for (int k = 2; k <= P; k <<= 1){
      for (int st = k >> 1; st > 0; st >>= 1){
        for (int i2 = tid; i2 < P; i2 += 1024){
          int j2 = i2 ^ st;
          if (j2 > i2){
            float a2 = cand[i2], b3 = cand[j2];
            bool up = ((i2 & k) == 0);
            if (up ? (a2 > b3) : (a2 < b3)){ cand[i2] = b3; cand[j2] = a2; }
          }
        }
        __syncthreads();
      }
    }
    if (tid == 0){
      float v1 = cand[2047 - cntBefore], v2 = cand[2048 - cntBefore];
      float med = 0.5f * (v1 + v2);
      astore(denom, 2.0f * med * med + 1e-8f);
    }
  }

  barno++; __syncthreads();
  if (tid == 0) gbar_leader(garr, gcnt, gen, barno);
  __syncthreads();

  // ---------- P2: CSR fill + per-row coef ----------
  if (e < N_Q * KNN){
    const int i = e / KNN, tt = e % KNN;
    const int j = nbr[e];
    const float wgt = aload(&wh[e]);
    const int p = aloadi(&rowptr[i]) + tt;
    colA[p] = j * N_C; wA[p] = wgt;          // plain stores; flushed by fence
    const int q = aloadi(&rowptr[j]) + KNN + atomicAdd(&fillc[j], 1);
    colA[q] = i * N_C; wA[q] = wgt;
  }
  const float cf = expf(-d2m / aload(denom)) / (aload(&rowsum[row]) + 1e-8f);
  const int p0  = aloadi(&rowptr[row]);
  const int p1v = aloadi(&rowptr[row + 1]);

  // one-time flush+invalidate so colA/wA/rowptr are plain-cacheable hereafter
  __builtin_amdgcn_fence(__ATOMIC_RELEASE, "agent");
  barno++; __syncthreads();
  if (tid == 0) gbar_leader(garr, gcnt, gen, barno);
  __syncthreads();
  __builtin_amdgcn_fence(__ATOMIC_ACQUIRE, "agent");

  // ---------- P3: y1 = step(y0) ----------
  float cur;
  {
    float s0 = 0.f, s1 = 0.f, s2 = 0.f, s3 = 0.f;
    int p = p0;
    for (; p + 4 <= p1v; p += 4){
      s0 = fmaf(wA[p    ], aload(&buf0[colA[p    ] + lane]), s0);
      s1 = fmaf(wA[p + 1], aload(&buf0[colA[p + 1] + lane]), s1);
      s2 = fmaf(wA[p + 2], aload(&buf0[colA[p + 2] + lane]), s2);
      s3 = fmaf(wA[p + 3], aload(&buf0[colA[p + 3] + lane]), s3);
    }
    for (; p < p1v; p++) s0 = fmaf(wA[p], aload(&buf0[colA[p] + lane]), s0);
    xv = -av + cf * ((s0 + s1) + (s2 + s3));
    m = wave_max64(xv); ee = expf(xv - m); ss = wave_sum64(ee);
    cur = ee / ss;
    astore(&buf1[row * N_C + lane], cur);
  }
  float dmax = wave_max64(fabsf(cur - prev));
  if (lane == 0) atomicMax(&sdmax, __float_as_int(dmax));
  barno++; __syncthreads();
  if (tid == 0){
    atomicMax((int*)&deltas[0], sdmax);
    sdmax = 0;
    __builtin_amdgcn_s_waitcnt(0);          // publish before arrive
    gbar_leader(garr, gcnt, gen, barno);
    sdelta = __int_as_float(aloadi((int*)&deltas[0]));
  }
  __syncthreads();
  float delta = sdelta;

  // ---------- P4: the while-loop ----------
  int par = 1;
  for (int t = 0;; t++){
    if (t >= MAX_ITER || delta < EPS_CONV) break;
    const float* src = par ? buf1 : buf0;
    float*       dst = par ? buf0 : buf1;
    float s0 = 0.f, s1 = 0.f, s2 = 0.f, s3 = 0.f;
    int p = p0;
    for (; p + 4 <= p1v; p += 4){
      s0 = fmaf(wA[p    ], aload(&src[colA[p    ] + lane]), s0);
      s1 = fmaf(wA[p + 1], aload(&src[colA[p + 1] + lane]), s1);
      s2 = fmaf(wA[p + 2], aload(&src[colA[p + 2] + lane]), s2);
      s3 = fmaf(wA[p + 3], aload(&src[colA[p + 3] + lane]), s3);
    }
    for (; p < p1v; p++) s0 = fmaf(wA[p], aload(&src[colA[p] + lane]), s0);
    xv = -av + cf * ((s0 + s1) + (s2 + s3));
    m = wave_max64(xv); ee = expf(xv - m); ss = wave_sum64(ee);
    float nxt = ee / ss;
    astore(&dst[row * N_C + lane], nxt);
    dmax = wave_max64(fabsf(nxt - cur));
    prev = cur; cur = nxt;
    if (lane == 0) atomicMax(&sdmax, __float_as_int(dmax));
    barno++; __syncthreads();
    if (tid == 0){
      atomicMax((int*)&deltas[t + 1], sdmax);
      sdmax = 0;
      __builtin_amdgcn_s_waitcnt(0);
      gbar_leader(garr, gcnt, gen, barno);
      sdelta = __int_as_float(aloadi((int*)&deltas[t + 1]));
    }
    __syncthreads();
    delta = sdelta;
    par ^= 1;
  }

  // argmax of y (prev); first occurrence on ties
  float bv = prev; int bi = lane;
  #pragma unroll
  for (int o = 32; o; o >>= 1){
    float ov = __shfl_xor(bv, o, 64); int oi = __shfl_xor(bi, o, 64);
    if (ov > bv || (ov == bv && oi < bi)){ bv = ov; bi = oi; }
  }
  if (lane == 0) out[row] = bi;
}

extern "C" void kernel_launch(void* const* d_in, const int* in_sizes, int n_in,
                              void* d_out, int out_size, void* d_ws, size_t ws_size,
                              hipStream_t stream)
{
  const float* feat_s = (const float*)d_in[0];
  const int*   y_s    = (const int*)d_in[1];
  const float* feat_q = (const float*)d_in[2];
  int* out = (int*)d_out;

  char* wp = (char*)d_ws;
  auto alloc = [&](size_t bytes) -> char* {
    char* p = wp;
    wp += (bytes + 255) & ~(size_t)255;
    return p;
  };
  float* Dq     = (float*)alloc((size_t)N_Q * N_Q * 4);      // 64 MB
  float* Pt     = (float*)alloc((size_t)DIM * N_C * 4);
  float* pn     = (float*)alloc(N_C * 4);
  float* qn     = (float*)alloc(N_Q * 4);
  float* d2min  = (float*)alloc(N_Q * 4);
  float* denom  = (float*)alloc(256);
  int*   nbr    = (int*)alloc((size_t)N_Q * KNN * 4);
  float* dnbr   = (float*)alloc((size_t)N_Q * KNN * 4);
  float* sigma  = (float*)alloc(N_Q * 4);
  float* wh     = (float*)alloc((size_t)N_Q * KNN * 4);
  int*   rowptr = (int*)alloc((N_Q + 1) * 4);
  int*   colA   = (int*)alloc((size_t)2 * N_Q * KNN * 4);
  float* wA     = (float*)alloc((size_t)2 * N_Q * KNN * 4);
  float* buf0   = (float*)alloc((size_t)N_Q * N_C * 4);
  float* buf1   = (float*)alloc((size_t)N_Q * N_C * 4);
  // contiguous zero-region: rowsum | indeg | fillc | deltas | gcnt/gen | garr
  char*  zbase  = alloc(N_Q*4 + N_Q*4 + N_Q*4 + 64*4 + 64*4 + 512*4);
  float* rowsum = (float*)(zbase);
  int*   indeg  = (int*)(zbase + N_Q*4);
  int*   fillc  = (int*)(zbase + N_Q*8);
  float* deltas = (float*)(zbase + N_Q*12);
  int*   syncw  = (int*)(zbase + N_Q*12 + 256);
  int*   garr   = (int*)(zbase + N_Q*12 + 512);
  const size_t zbytes = N_Q*12 + 256 + 256 + 2048;

  hipMemsetAsync(zbase, 0, zbytes, stream);

  proto_kernel  <<<N_C, 256, 0, stream>>>(feat_s, y_s, Pt, pn);
  rownorm_kernel<<<N_Q, 256, 0, stream>>>(feat_q, qn);
  dist_gemm     <<<dim3(N_Q/128, N_Q/128), 256, 0, stream>>>(feat_q, qn, Dq);
  topk_kernel   <<<N_Q, 256, 0, stream>>>(Dq, nbr, dnbr, sigma);

  int* gcnt = &syncw[0];
  int* gen  = &syncw[32];
  const float* Xq = feat_q;
  void* args[] = {&Xq, &Pt, &pn, &qn, &nbr, &dnbr, &sigma,
                  &d2min, &denom, &wh, &rowsum, &indeg, &rowptr, &fillc,
                  &colA, &wA, &buf0, &buf1, &deltas, &gcnt, &gen, &garr, &out};
  hipLaunchCooperativeKernel((void*)tail_loop, dim3(NBLK), dim3(1024), args, 0, stream);
}

// Round 8
// 811.576 us; speedup vs baseline: 9.8130x; 1.1743x over previous
//
#include <hip/hip_runtime.h>
#include <hip/hip_cooperative_groups.h>
#include <cfloat>
#include <cmath>

#define N_Q 4096
#define N_S 1600
#define DIM 1024
#define N_C 64
#define KNN 12
#define MAX_ITER 50
#define EPS_CONV 1e-4f
#define NBLK 256         // tail_loop grid size (16 groups x 16 blocks)

typedef _Float16 h8 __attribute__((ext_vector_type(8)));
typedef _Float16 h4 __attribute__((ext_vector_type(4)));
typedef float    f4 __attribute__((ext_vector_type(4)));

__device__ __forceinline__ float wave_max64(float v){
  #pragma unroll
  for (int o = 32; o; o >>= 1) v = fmaxf(v, __shfl_xor(v, o, 64));
  return v;
}
__device__ __forceinline__ float wave_sum64(float v){
  #pragma unroll
  for (int o = 32; o; o >>= 1) v += __shfl_xor(v, o, 64);
  return v;
}
__device__ __forceinline__ float wave_min64(float v){
  #pragma unroll
  for (int o = 32; o; o >>= 1) v = fminf(v, __shfl_xor(v, o, 64));
  return v;
}

// coherent (device-visible) element accesses for cross-block-communicated data
__device__ __forceinline__ float aload(const float* p){
  return __hip_atomic_load(p, __ATOMIC_RELAXED, __HIP_MEMORY_SCOPE_AGENT);
}
__device__ __forceinline__ void astore(float* p, float v){
  __hip_atomic_store(p, v, __ATOMIC_RELAXED, __HIP_MEMORY_SCOPE_AGENT);
}
__device__ __forceinline__ int aloadi(const int* p){
  return __hip_atomic_load(p, __ATOMIC_RELAXED, __HIP_MEMORY_SCOPE_AGENT);
}
__device__ __forceinline__ void astorei(int* p, int v){
  __hip_atomic_store(p, v, __ATOMIC_RELAXED, __HIP_MEMORY_SCOPE_AGENT);
}

// ---- prototypes: segment mean, stored TRANSPOSED Pt[f][c]; per-class sqnorm.
__global__ __launch_bounds__(256) void proto_kernel(
    const float* __restrict__ fs, const int* __restrict__ ys,
    float* __restrict__ Pt, float* __restrict__ pn)
{
  const int c = blockIdx.x, t = threadIdx.x;
  float a0 = 0.f, a1 = 0.f, a2 = 0.f, a3 = 0.f;
  int cnt = 0;
  for (int i = 0; i < N_S; i++){
    if (ys[i] == c){
      const float* r = fs + (size_t)i * DIM;
      a0 += r[t]; a1 += r[t + 256]; a2 += r[t + 512]; a3 += r[t + 768];
      cnt++;
    }
  }
  const float inv = 1.0f / fmaxf((float)cnt, 1.0f);
  const float v0 = a0*inv, v1 = a1*inv, v2 = a2*inv, v3 = a3*inv;
  Pt[(t      )*N_C + c] = v0;
  Pt[(t + 256)*N_C + c] = v1;
  Pt[(t + 512)*N_C + c] = v2;
  Pt[(t + 768)*N_C + c] = v3;
  __shared__ float red[256];
  red[t] = v0*v0 + v1*v1 + v2*v2 + v3*v3;
  __syncthreads();
  for (int o = 128; o; o >>= 1){ if (t < o) red[t] += red[t + o]; __syncthreads(); }
  if (t == 0) pn[c] = red[0];
}

// ---- per-row squared norm of feat_q
__global__ __launch_bounds__(256) void rownorm_kernel(
    const float* __restrict__ X, float* __restrict__ qn)
{
  const int i = blockIdx.x, t = threadIdx.x;
  const float* r = X + (size_t)i * DIM;
  float s = r[t]*r[t] + r[t+256]*r[t+256] + r[t+512]*r[t+512] + r[t+768]*r[t+768];
  __shared__ float red[256];
  red[t] = s; __syncthreads();
  for (int o = 128; o; o >>= 1){ if (t < o) red[t] += red[t + o]; __syncthreads(); }
  if (t == 0) qn[i] = red[0];
}

// ---- split fp32 X into f16 (hi, lo): x = hi + lo + O(2^-22 x).
__global__ __launch_bounds__(256) void split_kernel(
    const float* __restrict__ X, _Float16* __restrict__ Xh, _Float16* __restrict__ Xl)
{
  const int idx = (blockIdx.x * 256 + threadIdx.x) * 4;
  float4 v = *(const float4*)(X + idx);
  h4 hh, ll;
  hh[0] = (_Float16)v.x; ll[0] = (_Float16)(v.x - (float)hh[0]);
  hh[1] = (_Float16)v.y; ll[1] = (_Float16)(v.y - (float)hh[1]);
  hh[2] = (_Float16)v.z; ll[2] = (_Float16)(v.z - (float)hh[2]);
  hh[3] = (_Float16)v.w; ll[3] = (_Float16)(v.w - (float)hh[3]);
  *(h4*)(Xh + idx) = hh;
  *(h4*)(Xl + idx) = ll;
}

// ---- pairwise distances via f16 split-precision MFMA (Ootomo 3-term:
//      hi*hi + hi*lo + lo*hi, fp32 accumulate; error < fp32 FMA-chain noise).
//      128x128 tile, 4 waves in 2x2, each wave 64x64 = 4x4 mfma subtiles of
//      16x16x32. A and B frags use the IDENTICAL row-gather (X rows; B=X^T
//      operand), per m89/m120-verified layouts. No LDS, no barriers: frags
//      come straight from the L2-resident 16 MB split arrays.
__global__ __launch_bounds__(256, 2) void dist_mfma(
    const _Float16* __restrict__ Xh, const _Float16* __restrict__ Xl,
    const float* __restrict__ qn, float* __restrict__ Dq)
{
  const int t = threadIdx.x, w = t >> 6, l = t & 63;
  const int i0 = blockIdx.y * 128 + (w >> 1) * 64;
  const int j0 = blockIdx.x * 128 + (w & 1) * 64;
  const int fr = l & 15;            // fragment row (m for A, n for B)
  const int kq = (l >> 4) * 8;      // k offset within the 32-chunk

  f4 acc[4][4];
  #pragma unroll
  for (int a = 0; a < 4; a++)
    #pragma unroll
    for (int b = 0; b < 4; b++) acc[a][b] = (f4){0.f, 0.f, 0.f, 0.f};

  const _Float16* pAh = Xh + (size_t)(i0 + fr) * DIM + kq;
  const _Float16* pAl = Xl + (size_t)(i0 + fr) * DIM + kq;
  const _Float16* pBh = Xh + (size_t)(j0 + fr) * DIM + kq;
  const _Float16* pBl = Xl + (size_t)(j0 + fr) * DIM + kq;

  #pragma unroll 1
  for (int k0 = 0; k0 < DIM; k0 += 32){
    h8 ah[4], al[4];
    #pragma unroll
    for (int sm = 0; sm < 4; sm++){
      const size_t o = (size_t)(sm * 16) * DIM + k0;
      ah[sm] = *(const h8*)(pAh + o);
      al[sm] = *(const h8*)(pAl + o);
    }
    #pragma unroll
    for (int sn = 0; sn < 4; sn++){
      const size_t o = (size_t)(sn * 16) * DIM + k0;
      h8 bh = *(const h8*)(pBh + o);
      h8 bl = *(const h8*)(pBl + o);
      #pragma unroll
      for (int sm = 0; sm < 4; sm++){
        acc[sm][sn] = __builtin_amdgcn_mfma_f32_16x16x32_f16(ah[sm], bh, acc[sm][sn], 0, 0, 0);
        acc[sm][sn] = __builtin_amdgcn_mfma_f32_16x16x32_f16(ah[sm], bl, acc[sm][sn], 0, 0, 0);
        acc[sm][sn] = __builtin_amdgcn_mfma_f32_16x16x32_f16(al[sm], bh, acc[sm][sn], 0, 0, 0);
      }
    }
  }

  // epilogue: C/D layout col=lane&15, row=(lane>>4)*4+reg  [m89-verified]
  const int cr = (l >> 4) * 4;
  const int cc = l & 15;
  #pragma unroll
  for (int sm = 0; sm < 4; sm++){
    #pragma unroll
    for (int r = 0; r < 4; r++){
      const int row = i0 + sm * 16 + cr + r;
      const float qi = qn[row];
      float* dstrow = &Dq[(size_t)row * N_Q];
      #pragma unroll
      for (int sn = 0; sn < 4; sn++){
        const int col = j0 + sn * 16 + cc;
        float d2 = qi + qn[col] - 2.0f * acc[sm][sn][r];
        dstrow[col] = sqrtf(fmaxf(d2, 0.f));
      }
    }
  }
}

// ---- per-row 13 smallest (ties -> smaller index), row in registers.
__global__ __launch_bounds__(256) void topk_kernel(
    const float* __restrict__ Dq, int* __restrict__ nbr,
    float* __restrict__ dnbr, float* __restrict__ sigma)
{
  const int i = blockIdx.x, t = threadIdx.x;
  const float* row = Dq + (size_t)i * N_Q;
  float r[16];
  #pragma unroll
  for (int u = 0; u < 16; u++) r[u] = row[t + u * 256];

  __shared__ float pvf[4];
  __shared__ int   pif[4];
  __shared__ int   bwi_s;

  for (int s = 0; s < KNN + 1; s++){
    float best = FLT_MAX; int bj = 0x7fffffff;
    #pragma unroll
    for (int u = 0; u < 16; u++){
      float v = r[u];
      if (v < best){ best = v; bj = t + u * 256; }
    }
    #pragma unroll
    for (int o = 32; o; o >>= 1){
      float ov = __shfl_xor(best, o, 64); int oj = __shfl_xor(bj, o, 64);
      if (ov < best || (ov == best && oj < bj)){ best = ov; bj = oj; }
    }
    if ((t & 63) == 0){ pvf[t >> 6] = best; pif[t >> 6] = bj; }
    __syncthreads();
    if (t == 0){
      float bv = pvf[0]; int bi2 = pif[0];
      #pragma unroll
      for (int w2 = 1; w2 < 4; w2++){
        float v2 = pvf[w2]; int i2 = pif[w2];
        if (v2 < bv || (v2 == bv && i2 < bi2)){ bv = v2; bi2 = i2; }
      }
      bwi_s = bi2;
      if (s >= 1){ nbr[i*KNN + s - 1] = bi2; dnbr[i*KNN + s - 1] = bv; }
      if (s == KNN) sigma[i] = bv + 1e-8f;
    }
    __syncthreads();
    const int widx = bwi_s;
    if ((widx & 255) == t) r[widx >> 8] = FLT_MAX;
  }
}

// ============ hierarchical monotonic grid barrier (leader-only) ============
__device__ __forceinline__ void gbar_leader(int* garr, int* gcnt, int* gen, int target){
  const int g = blockIdx.x >> 4;
  int old = __hip_atomic_fetch_add(&garr[g * 32], 1, __ATOMIC_RELAXED, __HIP_MEMORY_SCOPE_AGENT);
  if ((old & 15) == 15){
    int o2 = __hip_atomic_fetch_add(gcnt, 1, __ATOMIC_RELAXED, __HIP_MEMORY_SCOPE_AGENT);
    if ((o2 & 15) == 15)
      __hip_atomic_fetch_add(gen, 1, __ATOMIC_RELAXED, __HIP_MEMORY_SCOPE_AGENT);
  }
  while (__hip_atomic_load(gen, __ATOMIC_RELAXED, __HIP_MEMORY_SCOPE_AGENT) < target)
    __builtin_amdgcn_s_sleep(1);
}

// ---- fused tail: a-matrix (in registers), wdeg, {scan | median | y0},
//      fill+coef, then the full while-loop. (unchanged from R7: 953us total,
//      tail no longer in top-5)
__global__ __launch_bounds__(1024, 4) void tail_loop(
    const float* __restrict__ Xq, const float* __restrict__ Pt,
    const float* __restrict__ pn, const float* __restrict__ qn,
    const int* __restrict__ nbr, const float* __restrict__ dnbr,
    const float* __restrict__ sigma,
    float* d2min, float* denom, float* wh,
    float* rowsum, int* indeg, int* rowptr, int* fillc,
    int* colA, float* wA, float* buf0, float* buf1, float* deltas,
    int* gcnt, int* gen, int* garr, int* __restrict__ out)
{
  __shared__ int   sdmax;
  __shared__ float sdelta;
  __shared__ int   ipart[1024];
  __shared__ int   hist[1024];
  __shared__ float cand[4096];
  __shared__ int   candn, b1s, b2s;

  const int tid  = threadIdx.x;
  const int lane = tid & 63;
  const int wv   = tid >> 6;
  const int row  = blockIdx.x * 16 + wv;
  int barno = 0;
  if (tid == 0) sdmax = 0;

  // ---------- P0a: a-row (kept in registers) ----------
  const float* xr = Xq + (size_t)row * DIM;
  float dp[8];
  #pragma unroll
  for (int u = 0; u < 8; u++) dp[u] = 0.f;
  for (int f = 0; f < DIM; f += 8){
    #pragma unroll
    for (int u = 0; u < 8; u++)
      dp[u] = fmaf(xr[f + u], Pt[(f + u) * N_C + lane], dp[u]);
  }
  const float dot = ((dp[0]+dp[1])+(dp[2]+dp[3])) + ((dp[4]+dp[5])+(dp[6]+dp[7]));
  const float av  = fmaxf(qn[row] + pn[lane] - 2.0f * dot, 0.0f);
  const float d2m = wave_min64(av);
  if (lane == 0) astore(&d2min[row], d2m);

  // ---------- P0b: edge weights + degrees ----------
  const int e = blockIdx.x * 1024 + tid;
  if (e < N_Q * KNN){
    const int i = e / KNN;
    const int j = nbr[e];
    float wgt = 0.5f * expf(-dnbr[e] / (sigma[i] * sigma[j]));
    astore(&wh[e], wgt);
    atomicAdd(&rowsum[i], wgt);
    atomicAdd(&rowsum[j], wgt);
    atomicAdd(&indeg[j], 1);
  }

  barno++; __syncthreads();
  if (tid == 0) gbar_leader(garr, gcnt, gen, barno);
  __syncthreads();

  // ---------- P1: y0 + scan (block 0) + median (block 1) ----------
  float xv = -av;
  float m = wave_max64(xv), ee = expf(xv - m), ss = wave_sum64(ee);
  float prev = ee / ss;
  astore(&buf0[row * N_C + lane], prev);

  if (blockIdx.x == 0){
    const int base = tid * 4;
    int c0 = aloadi(&indeg[base]),     c1 = aloadi(&indeg[base + 1]);
    int c2 = aloadi(&indeg[base + 2]), c3 = aloadi(&indeg[base + 3]);
    const int s4 = c0 + c1 + c2 + c3;
    ipart[tid] = s4;
    __syncthreads();
    for (int off = 1; off < 1024; off <<= 1){
      int v = (tid >= off) ? ipart[tid - off] : 0;
      __syncthreads();
      ipart[tid] += v;
      __syncthreads();
    }
    int run = ipart[tid] - s4;
    astorei(&rowptr[base    ], KNN * (base    ) + run); run += c0;
    astorei(&rowptr[base + 1], KNN * (base + 1) + run); run += c1;
    astorei(&rowptr[base + 2], KNN * (base + 2) + run); run += c2;
    astorei(&rowptr[base + 3], KNN * (base + 3) + run);
    if (tid == 1023) astorei(&rowptr[N_Q], KNN * N_Q + ipart[1023]);
  }
  if (blockIdx.x == 1){
    const int base = tid * 4;
    float dv[4];
    #pragma unroll
    for (int u = 0; u < 4; u++) dv[u] = sqrtf(aload(&d2min[base + u]));
    float mn = fminf(fminf(dv[0], dv[1]), fminf(dv[2], dv[3]));
    float mx = fmaxf(fmaxf(dv[0], dv[1]), fmaxf(dv[2], dv[3]));
    mn = wave_min64(mn); mx = wave_max64(mx);
    if (lane == 0){ cand[wv] = mn; cand[wv + 16] = mx; }
    __syncthreads();
    if (tid == 0){
      float a = cand[0], b = cand[16];
      for (int k = 1; k < 16; k++){ a = fminf(a, cand[k]); b = fmaxf(b, cand[16 + k]); }
      cand[32] = a; cand[33] = b;
    }
    __syncthreads();
    mn = cand[32]; mx = cand[33];
    const float rng = mx - mn;
    const float scale = (rng > 0.f) ? (1024.0f / rng) : 0.f;
    hist[tid] = 0;
    __syncthreads();
    int bidx[4];
    #pragma unroll
    for (int u = 0; u < 4; u++){
      int b = (int)((dv[u] - mn) * scale);
      b = b < 0 ? 0 : (b > 1023 ? 1023 : b);
      bidx[u] = b;
      atomicAdd(&hist[b], 1);
    }
    __syncthreads();
    for (int off = 1; off < 1024; off <<= 1){
      int v = (tid >= off) ? hist[tid - off] : 0;
      __syncthreads();
      hist[tid] += v;
      __syncthreads();
    }
    if (hist[tid] >= 2048 && (tid == 0 || hist[tid - 1] < 2048)) b1s = tid;
    if (hist[tid] >= 2049 && (tid == 0 || hist[tid - 1] < 2049)) b2s = tid;
    if (tid == 0) candn = 0;
    __syncthreads();
    const int b1 = b1s, b2 = b2s;
    const int cntBefore = (b1 > 0) ? hist[b1 - 1] : 0;
    #pragma unroll
    for (int u = 0; u < 4; u++){
      if (bidx[u] >= b1 && bidx[u] <= b2){
        int pos = atomicAdd(&candn, 1);
        cand[pos] = dv[u];
      }
    }
    __syncthreads();
    const int mcnt = candn;
    int P = 2; while (P < mcnt) P <<= 1;
    for (int i2 = mcnt + tid; i2 < P; i2 += 1024) cand[i2] = FLT_MAX;
    __syncthreads();
    for (int k = 2; k <= P; k <<= 1){
      for (int st = k >> 1; st > 0; st >>= 1){
        for (int i2 = tid; i2 < P; i2 += 1024){
          int j2 = i2 ^ st;
          if (j2 > i2){
            float a2 = cand[i2], b3 = cand[j2];
            bool up = ((i2 & k) == 0);
            if (up ? (a2 > b3) : (a2 < b3)){ cand[i2] = b3; cand[j2] = a2; }
          }
        }
        __syncthreads();
      }
    }
    if (tid == 0){
      float v1 = cand[2047 - cntBefore], v2 = cand[2048 - cntBefore];
      float med = 0.5f * (v1 + v2);
      astore(denom, 2.0f * med * med + 1e-8f);
    }
  }

  barno++; __syncthreads();
  if (tid == 0) gbar_leader(garr, gcnt, gen, barno);
  __syncthreads();

  // ---------- P2: CSR fill + per-row coef ----------
  if (e < N_Q * KNN){
    const int i = e / KNN, tt = e % KNN;
    const int j = nbr[e];
    const float wgt = aload(&wh[e]);
    const int p = aloadi(&rowptr[i]) + tt;
    colA[p] = j * N_C; wA[p] = wgt;
    const int q = aloadi(&rowptr[j]) + KNN + atomicAdd(&fillc[j], 1);
    colA[q] = i * N_C; wA[q] = wgt;
  }
  const float cf = expf(-d2m / aload(denom)) / (aload(&rowsum[row]) + 1e-8f);
  const int p0  = aloadi(&rowptr[row]);
  const int p1v = aloadi(&rowptr[row + 1]);

  __builtin_amdgcn_fence(__ATOMIC_RELEASE, "agent");
  barno++; __syncthreads();
  if (tid == 0) gbar_leader(garr, gcnt, gen, barno);
  __syncthreads();
  __builtin_amdgcn_fence(__ATOMIC_ACQUIRE, "agent");

  // ---------- P3: y1 = step(y0) ----------
  float cur;
  {
    float s0 = 0.f, s1 = 0.f, s2 = 0.f, s3 = 0.f;
    int p = p0;
    for (; p + 4 <= p1v; p += 4){
      s0 = fmaf(wA[p    ], aload(&buf0[colA[p    ] + lane]), s0);
      s1 = fmaf(wA[p + 1], aload(&buf0[colA[p + 1] + lane]), s1);
      s2 = fmaf(wA[p + 2], aload(&buf0[colA[p + 2] + lane]), s2);
      s3 = fmaf(wA[p + 3], aload(&buf0[colA[p + 3] + lane]), s3);
    }
    for (; p < p1v; p++) s0 = fmaf(wA[p], aload(&buf0[colA[p] + lane]), s0);
    xv = -av + cf * ((s0 + s1) + (s2 + s3));
    m = wave_max64(xv); ee = expf(xv - m); ss = wave_sum64(ee);
    cur = ee / ss;
    astore(&buf1[row * N_C + lane], cur);
  }
  float dmax = wave_max64(fabsf(cur - prev));
  if (lane == 0) atomicMax(&sdmax, __float_as_int(dmax));
  barno++; __syncthreads();
  if (tid == 0){
    atomicMax((int*)&deltas[0], sdmax);
    sdmax = 0;
    __builtin_amdgcn_s_waitcnt(0);
    gbar_leader(garr, gcnt, gen, barno);
    sdelta = __int_as_float(aloadi((int*)&deltas[0]));
  }
  __syncthreads();
  float delta = sdelta;

  // ---------- P4: the while-loop ----------
  int par = 1;
  for (int t = 0;; t++){
    if (t >= MAX_ITER || delta < EPS_CONV) break;
    const float* src = par ? buf1 : buf0;
    float*       dst = par ? buf0 : buf1;
    float s0 = 0.f, s1 = 0.f, s2 = 0.f, s3 = 0.f;
    int p = p0;
    for (; p + 4 <= p1v; p += 4){
      s0 = fmaf(wA[p    ], aload(&src[colA[p    ] + lane]), s0);
      s1 = fmaf(wA[p + 1], aload(&src[colA[p + 1] + lane]), s1);
      s2 = fmaf(wA[p + 2], aload(&src[colA[p + 2] + lane]), s2);
      s3 = fmaf(wA[p + 3], aload(&src[colA[p + 3] + lane]), s3);
    }
    for (; p < p1v; p++) s0 = fmaf(wA[p], aload(&src[colA[p] + lane]), s0);
    xv = -av + cf * ((s0 + s1) + (s2 + s3));
    m = wave_max64(xv); ee = expf(xv - m); ss = wave_sum64(ee);
    float nxt = ee / ss;
    astore(&dst[row * N_C + lane], nxt);
    dmax = wave_max64(fabsf(nxt - cur));
    prev = cur; cur = nxt;
    if (lane == 0) atomicMax(&sdmax, __float_as_int(dmax));
    barno++; __syncthreads();
    if (tid == 0){
      atomicMax((int*)&deltas[t + 1], sdmax);
      sdmax = 0;
      __builtin_amdgcn_s_waitcnt(0);
      gbar_leader(garr, gcnt, gen, barno);
      sdelta = __int_as_float(aloadi((int*)&deltas[t + 1]));
    }
    __syncthreads();
    delta = sdelta;
    par ^= 1;
  }

  // argmax of y (prev); first occurrence on ties
  float bv = prev; int bi = lane;
  #pragma unroll
  for (int o = 32; o; o >>= 1){
    float ov = __shfl_xor(bv, o, 64); int oi = __shfl_xor(bi, o, 64);
    if (ov > bv || (ov == bv && oi < bi)){ bv = ov; bi = oi; }
  }
  if (lane == 0) out[row] = bi;
}

extern "C" void kernel_launch(void* const* d_in, const int* in_sizes, int n_in,
                              void* d_out, int out_size, void* d_ws, size_t ws_size,
                              hipStream_t stream)
{
  const float* feat_s = (const float*)d_in[0];
  const int*   y_s    = (const int*)d_in[1];
  const float* feat_q = (const float*)d_in[2];
  int* out = (int*)d_out;

  char* wp = (char*)d_ws;
  auto alloc = [&](size_t bytes) -> char* {
    char* p = wp;
    wp += (bytes + 255) & ~(size_t)255;
    return p;
  };
  float*     Dq  = (float*)alloc((size_t)N_Q * N_Q * 4);     // 64 MB
  _Float16*  Xh  = (_Float16*)alloc((size_t)N_Q * DIM * 2);  // 8 MB
  _Float16*  Xl  = (_Float16*)alloc((size_t)N_Q * DIM * 2);  // 8 MB
  float* Pt     = (float*)alloc((size_t)DIM * N_C * 4);
  float* pn     = (float*)alloc(N_C * 4);
  float* qn     = (float*)alloc(N_Q * 4);
  float* d2min  = (float*)alloc(N_Q * 4);
  float* denom  = (float*)alloc(256);
  int*   nbr    = (int*)alloc((size_t)N_Q * KNN * 4);
  float* dnbr   = (float*)alloc((size_t)N_Q * KNN * 4);
  float* sigma  = (float*)alloc(N_Q * 4);
  float* wh     = (float*)alloc((size_t)N_Q * KNN * 4);
  int*   rowptr = (int*)alloc((N_Q + 1) * 4);
  int*   colA   = (int*)alloc((size_t)2 * N_Q * KNN * 4);
  float* wA     = (float*)alloc((size_t)2 * N_Q * KNN * 4);
  float* buf0   = (float*)alloc((size_t)N_Q * N_C * 4);
  float* buf1   = (float*)alloc((size_t)N_Q * N_C * 4);
  char*  zbase  = alloc(N_Q*4 + N_Q*4 + N_Q*4 + 64*4 + 64*4 + 512*4);
  float* rowsum = (float*)(zbase);
  int*   indeg  = (int*)(zbase + N_Q*4);
  int*   fillc  = (int*)(zbase + N_Q*8);
  float* deltas = (float*)(zbase + N_Q*12);
  int*   syncw  = (int*)(zbase + N_Q*12 + 256);
  int*   garr   = (int*)(zbase + N_Q*12 + 512);
  const size_t zbytes = N_Q*12 + 256 + 256 + 2048;

  hipMemsetAsync(zbase, 0, zbytes, stream);

  proto_kernel  <<<N_C, 256, 0, stream>>>(feat_s, y_s, Pt, pn);
  rownorm_kernel<<<N_Q, 256, 0, stream>>>(feat_q, qn);
  split_kernel  <<<(N_Q * DIM) / (256 * 4), 256, 0, stream>>>(feat_q, Xh, Xl);
  dist_mfma     <<<dim3(N_Q/128, N_Q/128), 256, 0, stream>>>(Xh, Xl, qn, Dq);
  topk_kernel   <<<N_Q, 256, 0, stream>>>(Dq, nbr, dnbr, sigma);

  int* gcnt = &syncw[0];
  int* gen  = &syncw[32];
  const float* Xq = feat_q;
  void* args[] = {&Xq, &Pt, &pn, &qn, &nbr, &dnbr, &sigma,
                  &d2min, &denom, &wh, &rowsum, &indeg, &rowptr, &fillc,
                  &colA, &wA, &buf0, &buf1, &deltas, &gcnt, &gen, &garr, &out};
  hipLaunchCooperativeKernel((void*)tail_loop, dim3(NBLK), dim3(1024), args, 0, stream);
}